// Round 1
// baseline (1557.785 us; speedup 1.0000x reference)
//
#include <hip/hip_runtime.h>
#include <math.h>

typedef unsigned short u16;
typedef unsigned int u32;
typedef u16 u16x4 __attribute__((ext_vector_type(4)));
typedef float f32x2 __attribute__((ext_vector_type(2)));
typedef float f32x4 __attribute__((ext_vector_type(4)));
typedef __bf16 bf16x8 __attribute__((ext_vector_type(8)));

#define BM 128
#define BN 128
#define BK 32
#define LSTR 40  // u16 elems per LDS row (32 data + 8 pad) = 80 B

__device__ __forceinline__ u16 f2bf(float f){
  u32 u = __builtin_bit_cast(u32, f);
  u32 r = u + 0x7FFFu + ((u >> 16) & 1u);
  return (u16)(r >> 16);
}
__device__ __forceinline__ float bf2f(u16 h){
  u32 u = ((u32)h) << 16;
  return __builtin_bit_cast(float, u);
}

// C[m][n] = sum_k A[m][k] * W[n][k] + bias[n]
// SPLIT: 3-pass hi/lo bf16 (fp32-accurate). GATHER: A = [x | h_prev | surfaced].
// FIO: W selected per 1024-col segment from {W0,W1,W2}.
template<bool SPLIT, bool GATHER, bool FIO>
__global__ __launch_bounds__(256) void gemm_bt(
    const float* __restrict__ A, int lda,
    const float* __restrict__ Xs, const float* __restrict__ Hs, const float* __restrict__ Ss,
    const float* __restrict__ W0, const float* __restrict__ W1, const float* __restrict__ W2,
    const float* __restrict__ b0, const float* __restrict__ b1, const float* __restrict__ b2,
    float* __restrict__ C, int ldc, int K)
{
  __shared__ u16 sAh[BM*LSTR];
  __shared__ u16 sAl[BM*LSTR];
  __shared__ u16 sBh[BN*LSTR];
  __shared__ u16 sBl[BN*LSTR];

  const int tid = threadIdx.x;
  const int m0 = blockIdx.y * BM;
  const int n0 = blockIdx.x * BN;

  const float* W = W0;
  const float* bias = b0;
  int nw = n0;
  if constexpr (FIO){
    int seg = n0 >> 10;
    W    = (seg==0) ? W0 : (seg==1 ? W1 : W2);
    bias = (seg==0) ? b0 : (seg==1 ? b1 : b2);
    nw = n0 & 1023;
  }

  const int wave = tid >> 6;
  const int lane = tid & 63;
  const int wm = wave >> 1;
  const int wn = wave & 1;
  const int l16 = lane & 15;
  const int lk8 = (lane >> 4) * 8;

  f32x4 acc[4][4];
  #pragma unroll
  for (int a=0;a<4;++a)
    #pragma unroll
    for (int bq=0;bq<4;++bq){
      f32x4 z = {0.f,0.f,0.f,0.f};
      acc[a][bq] = z;
    }

  for (int k0 = 0; k0 < K; k0 += BK){
    // ---- stage f32 -> split bf16 hi/lo in LDS ----
    #pragma unroll
    for (int i=0;i<4;++i){
      int flat = tid + i*256;
      int r  = flat >> 3;
      int c4 = flat & 7;
      int kk = k0 + c4*4;
      const float* srcA;
      if constexpr (GATHER){
        if (kk < 1024)      srcA = Xs + (size_t)(m0 + r)*1024 + kk;
        else if (kk < 3072) srcA = Hs + (size_t)(m0 + r)*2048 + (kk - 1024);
        else                srcA = Ss + (size_t)(m0 + r)*2048 + (kk - 3072);
      } else {
        srcA = A + (size_t)(m0 + r)*lda + kk;
      }
      f32x4 va = *(const f32x4*)srcA;
      f32x4 vb = *(const f32x4*)(W + (size_t)(nw + r)*K + kk);
      u16x4 ah, bh, al, bl;
      #pragma unroll
      for (int j=0;j<4;++j){
        u16 hA = f2bf(va[j]); ah[j] = hA;
        u16 hB = f2bf(vb[j]); bh[j] = hB;
        if constexpr (SPLIT){
          al[j] = f2bf(va[j] - bf2f(hA));
          bl[j] = f2bf(vb[j] - bf2f(hB));
        }
      }
      int o = r*LSTR + c4*4;
      *(u16x4*)&sAh[o] = ah;
      *(u16x4*)&sBh[o] = bh;
      if constexpr (SPLIT){
        *(u16x4*)&sAl[o] = al;
        *(u16x4*)&sBl[o] = bl;
      }
    }
    __syncthreads();

    // ---- fragments + MFMA ----
    bf16x8 fah[4], fbh[4], fal[4], fbl[4];
    #pragma unroll
    for (int f=0; f<4; ++f){
      int ra  = (wm*64 + f*16 + l16)*LSTR + lk8;
      int rb2 = (wn*64 + f*16 + l16)*LSTR + lk8;
      fah[f] = *(const bf16x8*)&sAh[ra];
      fbh[f] = *(const bf16x8*)&sBh[rb2];
      if constexpr (SPLIT){
        fal[f] = *(const bf16x8*)&sAl[ra];
        fbl[f] = *(const bf16x8*)&sBl[rb2];
      }
    }
    #pragma unroll
    for (int fm=0; fm<4; ++fm){
      #pragma unroll
      for (int fn=0; fn<4; ++fn){
        acc[fm][fn] = __builtin_amdgcn_mfma_f32_16x16x32_bf16(fah[fm], fbh[fn], acc[fm][fn], 0,0,0);
        if constexpr (SPLIT){
          acc[fm][fn] = __builtin_amdgcn_mfma_f32_16x16x32_bf16(fal[fm], fbh[fn], acc[fm][fn], 0,0,0);
          acc[fm][fn] = __builtin_amdgcn_mfma_f32_16x16x32_bf16(fah[fm], fbl[fn], acc[fm][fn], 0,0,0);
        }
      }
    }
    __syncthreads();
  }

  // ---- epilogue: C = acc + bias ----
  #pragma unroll
  for (int fm=0; fm<4; ++fm){
    int grow = m0 + wm*64 + fm*16 + (lane>>4)*4;
    #pragma unroll
    for (int fn=0; fn<4; ++fn){
      int lcol = wn*64 + fn*16 + l16;
      float bb = bias[nw + lcol];
      #pragma unroll
      for (int r2=0;r2<4;++r2){
        C[(size_t)(grow + r2)*ldc + (n0 + lcol)] = acc[fm][fn][r2] + bb;
      }
    }
  }
}

// surfaced = d_normed * d_scale * T, T = cos^2((phase(xc)-phase(d))/2)
__global__ __launch_bounds__(256) void prep_surf(
    const float* __restrict__ xc, const float* __restrict__ dp,
    float* __restrict__ surf, int n)
{
  int i = blockIdx.x*256 + threadIdx.x;
  if (i >= n) return;
  f32x2 z = *(const f32x2*)(xc + 2*(size_t)i);
  f32x2 d = *(const f32x2*)(dp + 2*(size_t)i);
  float pa = atan2f(z[1], z[0] + 1e-10f);
  float pb = atan2f(d[1], d[0] + 1e-10f);
  float cc = cosf((pa - pb)*0.5f);
  float T = cc*cc;
  float dmag = sqrtf(d[0]*d[0] + d[1]*d[1] + 1e-8f);
  float dscale = sqrtf(fminf(fmaxf(dmag, 1e-6f), 20.0f));
  float s = T * dscale / (dmag + 1e-8f);
  f32x2 o; o[0] = d[0]*s; o[1] = d[1]*s;
  *(f32x2*)(surf + 2*(size_t)i) = o;
}

__global__ __launch_bounds__(256) void epilogue(
    const float* __restrict__ raw, const float* __restrict__ c_prev,
    const float* __restrict__ d_prev, const float* __restrict__ b_prev,
    const float* __restrict__ theta, float* __restrict__ out)
{
  const int b = blockIdx.x;
  const int tid = threadIdx.x;
  float* Hout = out;
  float* Cout = out + (size_t)8388608;
  float* Dout = out + (size_t)16777216;
  float* Bout = out + (size_t)25165824;
  const float bp = b_prev[b];
  const float inv_t = 1.0f / (2.0f*bp + 1e-4f);
  float conv_acc = 0.f, emer_acc = 0.f;
  const size_t rb = (size_t)b*5120;
  const float p23 = (float)(2.0/3.0);

  #pragma unroll
  for (int j=0;j<4;++j){
    int h = tid + j*256;
    float fr = raw[rb + h];
    float ir = raw[rb + 1024 + h];
    float og = raw[rb + 2048 + h];
    float g0 = raw[rb + 3072 + h];
    float g1 = raw[rb + 4096 + h];

    float mx = fmaxf(fr, fmaxf(ir, og));
    float ef = expf((fr-mx)*inv_t);
    float ei = expf((ir-mx)*inv_t);
    float eo = expf((og-mx)*inv_t);
    float inv_s = 1.0f/(ef+ei+eo);
    float ft = ef*inv_s, it = ei*inv_s, ot = eo*inv_s;

    f32x2 cp = *(const f32x2*)(c_prev + 2*((size_t)b*1024 + h));
    f32x2 dp = *(const f32x2*)(d_prev + 2*((size_t)b*1024 + h));

    float r0 = (1.f-ft)*cp[0], r1 = (1.f-ft)*cp[1];
    float rm2 = r0*r0 + r1*r1 + 1e-8f;
    conv_acc += rm2;
    float rmag = sqrtf(rm2);
    float mm = fmaxf(rmag, 1e-8f);
    float cm = powf(mm, p23);
    float ph = atan2f(r1, r0 + 1e-10f);
    float comp0 = fminf(fmaxf(cm * cosf(ph), -10.f), 10.f);
    float comp1 = fminf(fmaxf(cm * sinf(ph), -10.f), 10.f);

    float d0 = dp[0] + 0.01f*comp0;
    float d1 = dp[1] + 0.01f*comp1;
    float dmn = sqrtf(d0*d0 + d1*d1 + 1e-8f);
    if (dmn > 20.f){ float sc = 20.f/dmn; d0*=sc; d1*=sc; }

    float gt0 = tanhf(g0), gt1 = tanhf(g1);
    float cu0 = ft*cp[0] + it*gt0;
    float cu1 = ft*cp[1] + it*gt1;
    float th = theta[h];
    float cth = cosf(th), sth = sinf(th);
    float c0 = cth*cu0 - sth*cu1;
    float c1 = sth*cu0 + cth*cu1;
    float cs0 = tanhf(c0), cs1 = tanhf(c1);
    float hr0 = ot*cs0, hr1 = ot*cs1;

    float pa = atan2f(hr1, hr0 + 1e-10f);
    float pb2 = atan2f(d1, d0 + 1e-10f);
    float cg = cosf((pa - pb2)*0.5f);
    float G = cg*cg;
    float h0 = G*hr0, h1 = G*hr1;
    emer_acc += h0*h0 + h1*h1 + 1e-8f;

    h0 = (h0==h0)?h0:0.f;  h1 = (h1==h1)?h1:0.f;
    c0 = (c0==c0)?c0:0.f;  c1 = (c1==c1)?c1:0.f;
    d0 = (d0==d0)?d0:0.f;  d1 = (d1==d1)?d1:0.f;

    size_t oi = 2*((size_t)b*1024 + h);
    f32x2 w;
    w[0]=h0; w[1]=h1; *(f32x2*)(Hout+oi) = w;
    w[0]=c0; w[1]=c1; *(f32x2*)(Cout+oi) = w;
    w[0]=d0; w[1]=d1; *(f32x2*)(Dout+oi) = w;
  }

  // block reduction for b_t
  #pragma unroll
  for (int off=32; off; off>>=1){
    conv_acc += __shfl_down(conv_acc, off);
    emer_acc += __shfl_down(emer_acc, off);
  }
  __shared__ float sred[8];
  int wv = tid>>6, ln = tid&63;
  if (ln==0){ sred[wv]=conv_acc; sred[4+wv]=emer_acc; }
  __syncthreads();
  if (tid==0){
    float cv = sred[0]+sred[1]+sred[2]+sred[3];
    float em = sred[4]+sred[5]+sred[6]+sred[7];
    float bm = cv/(cv+em+1e-8f);
    float bt = 0.99f*bp + 0.01f*bm;
    bt = (bt==bt)?bt:0.5f;
    Bout[b] = bt;
  }
}

extern "C" void kernel_launch(void* const* d_in, const int* in_sizes, int n_in,
                              void* d_out, int out_size, void* d_ws, size_t ws_size,
                              hipStream_t stream)
{
  const float* x_t    = (const float*)d_in[0];
  const float* h_prev = (const float*)d_in[1];
  const float* c_prev = (const float*)d_in[2];
  const float* d_prev = (const float*)d_in[3];
  const float* b_prev = (const float*)d_in[4];
  const float* Wf_w   = (const float*)d_in[5];
  const float* Wf_b   = (const float*)d_in[6];
  const float* Wi_w   = (const float*)d_in[7];
  const float* Wi_b   = (const float*)d_in[8];
  const float* Wo_w   = (const float*)d_in[9];
  const float* Wo_b   = (const float*)d_in[10];
  const float* Wc_w   = (const float*)d_in[11];
  const float* Wc_b   = (const float*)d_in[12];
  const float* Wr_w   = (const float*)d_in[13];
  const float* Wr_b   = (const float*)d_in[14];
  const float* theta  = (const float*)d_in[15];

  float* raw  = (float*)d_ws;                     // 4096*5120 f32
  float* xc   = raw + (size_t)4096*5120;          // 4096*2048 f32
  float* surf = xc  + (size_t)4096*2048;          // 4096*2048 f32

  dim3 blk(256);

  // GEMM1: xc = x_t @ Wr^T + Wr_b   (split precision: feeds gate raws via surfaced)
  gemm_bt<true,false,false><<<dim3(16,32), blk, 0, stream>>>(
      x_t, 1024, nullptr, nullptr, nullptr,
      Wr_w, nullptr, nullptr, Wr_b, nullptr, nullptr,
      xc, 2048, 1024);

  prep_surf<<<16384, blk, 0, stream>>>(xc, d_prev, surf, 4096*1024);

  // f/i/o gates fused: raw[:, 0:3072], split precision
  gemm_bt<true,true,true><<<dim3(24,32), blk, 0, stream>>>(
      nullptr, 0, x_t, h_prev, surf,
      Wf_w, Wi_w, Wo_w, Wf_b, Wi_b, Wo_b,
      raw, 5120, 5120);

  // g gates: raw[:, 3072:5120], single-pass bf16 (tanh is 1-Lipschitz)
  gemm_bt<false,true,false><<<dim3(16,32), blk, 0, stream>>>(
      nullptr, 0, x_t, h_prev, surf,
      Wc_w, nullptr, nullptr, Wc_b, nullptr, nullptr,
      raw + 3072, 5120, 5120);

  epilogue<<<4096, blk, 0, stream>>>(raw, c_prev, d_prev, b_prev, theta, (float*)d_out);
}

// Round 2
// 1045.405 us; speedup vs baseline: 1.4901x; 1.4901x over previous
//
#include <hip/hip_runtime.h>
#include <math.h>

typedef unsigned short u16;
typedef unsigned int u32;
typedef u16 u16x4 __attribute__((ext_vector_type(4)));
typedef float f32x2 __attribute__((ext_vector_type(2)));
typedef float f32x4 __attribute__((ext_vector_type(4)));
typedef __bf16 bf16x8 __attribute__((ext_vector_type(8)));

__device__ __forceinline__ u16 f2bf(float f){
  u32 u = __builtin_bit_cast(u32, f);
  u32 r = u + 0x7FFFu + ((u >> 16) & 1u);
  return (u16)(r >> 16);
}
__device__ __forceinline__ float bf2f(u16 h){
  u32 u = ((u32)h) << 16;
  return __builtin_bit_cast(float, u);
}

typedef __attribute__((address_space(1))) const unsigned int gas_u32;
typedef __attribute__((address_space(3))) unsigned int las_u32;
__device__ __forceinline__ void gload_lds16(const void* g, void* l){
  __builtin_amdgcn_global_load_lds((gas_u32*)g, (las_u32*)l, 16, 0, 0);
}

// ---------------- converts ----------------
__global__ __launch_bounds__(256) void cvt_hi(const float* __restrict__ in, u16* __restrict__ out, int n4){
  int i = blockIdx.x*256 + threadIdx.x;
  if (i >= n4) return;
  f32x4 v = *(const f32x4*)(in + (size_t)i*4);
  u16x4 o;
  #pragma unroll
  for (int j=0;j<4;++j) o[j]=f2bf(v[j]);
  *(u16x4*)(out + (size_t)i*4) = o;
}

__global__ __launch_bounds__(256) void cvt_hilo(const float* __restrict__ in, u16* __restrict__ hi, u16* __restrict__ lo, int n4){
  int i = blockIdx.x*256 + threadIdx.x;
  if (i >= n4) return;
  f32x4 v = *(const f32x4*)(in + (size_t)i*4);
  u16x4 oh, ol;
  #pragma unroll
  for (int j=0;j<4;++j){ u16 h=f2bf(v[j]); oh[j]=h; ol[j]=f2bf(v[j]-bf2f(h)); }
  *(u16x4*)(hi + (size_t)i*4) = oh;
  *(u16x4*)(lo + (size_t)i*4) = ol;
}

// x,h -> cA_hi[:,0:3072] (bf16), x also -> x_lo
__global__ __launch_bounds__(256) void cvt_xh(const float* __restrict__ x, const float* __restrict__ h,
                                              u16* __restrict__ cA, u16* __restrict__ xlo){
  int b = blockIdx.y;
  int c0 = (blockIdx.x*256 + threadIdx.x)*4;  // grid.x=3 -> c0 in [0,3072)
  f32x4 v;
  if (c0 < 1024) v = *(const f32x4*)(x + (size_t)b*1024 + c0);
  else           v = *(const f32x4*)(h + (size_t)b*2048 + (c0-1024));
  u16x4 hi4;
  #pragma unroll
  for (int j=0;j<4;++j) hi4[j]=f2bf(v[j]);
  *(u16x4*)(cA + (size_t)b*5120 + c0) = hi4;
  if (c0 < 1024){
    u16x4 lo4;
    #pragma unroll
    for (int j=0;j<4;++j) lo4[j]=f2bf(v[j]-bf2f(hi4[j]));
    *(u16x4*)(xlo + (size_t)b*1024 + c0) = lo4;
  }
}

// surfaced: f32 buffer + bf16 into cA_hi[:,3072:5120]
__global__ __launch_bounds__(256) void prep_surf(const float* __restrict__ xc, const float* __restrict__ dp,
                                                 float* __restrict__ surf, u16* __restrict__ cA){
  int i = blockIdx.x*256 + threadIdx.x;   // over 4096*1024
  int b = i >> 10, h = i & 1023;
  f32x2 z = *(const f32x2*)(xc + 2*(size_t)i);
  f32x2 d = *(const f32x2*)(dp + 2*(size_t)i);
  float pa = atan2f(z[1], z[0] + 1e-10f);
  float pb = atan2f(d[1], d[0] + 1e-10f);
  float cc = cosf((pa - pb)*0.5f);
  float T = cc*cc;
  float dmag = sqrtf(d[0]*d[0] + d[1]*d[1] + 1e-8f);
  float dscale = sqrtf(fminf(fmaxf(dmag, 1e-6f), 20.0f));
  float s = T * dscale / (dmag + 1e-8f);
  float o0 = d[0]*s, o1 = d[1]*s;
  *(f32x2*)(surf + 2*(size_t)i) = f32x2{o0, o1};
  u32 pk = (u32)f2bf(o0) | ((u32)f2bf(o1) << 16);
  *(u32*)&cA[(size_t)b*5120 + 3072 + 2*h] = pk;
}

// rows with small temperature -> need precise raws
__global__ __launch_bounds__(256) void flag_rows(const float* __restrict__ bp, int* __restrict__ out){
  __shared__ int cnt;
  if (threadIdx.x==0) cnt=0;
  __syncthreads();
  for (int i=threadIdx.x; i<4096; i+=256){
    if (bp[i] < 0.04f){ int p = atomicAdd(&cnt,1); out[1+p]=i; }
  }
  __syncthreads();
  if (threadIdx.x==0) out[0]=cnt;
}

// ---------------- fast pure-bf16 GEMM (m97 structure + 4-way swizzle) ----------------
// C[m][n] = sum_k A[m][k]*B[n][k] + bias(n).  SPLIT: 3-pass hi/lo.
template<bool SPLIT, bool OUTBF, bool BIAS2>
__global__ __launch_bounds__(256) void gemm_fast(
    const u16* __restrict__ Ah, int lda,
    const u16* __restrict__ Al, int ldal,
    const u16* __restrict__ Bh, int ldb,
    const u16* __restrict__ Bl,
    const float* __restrict__ bias0, const float* __restrict__ bias1,
    float* __restrict__ Cf, u16* __restrict__ Cb, int ldc, int K)
{
  __shared__ u16 sAh[128*32];
  __shared__ u16 sBh[128*32];
  __shared__ u16 sAl[SPLIT?128*32:8];
  __shared__ u16 sBl[SPLIT?128*32:8];

  const int tid=threadIdx.x, lane=tid&63, w=tid>>6;
  const int m0=blockIdx.y*128, n0=blockIdx.x*128;
  const int wm=w>>1, wn=w&1, l16=lane&15, hi16=lane>>4;

  // staging: 512 chunks of 16B per 8KB tile; chunk c -> row=c>>2, slot=c&3,
  // source slot pre-swizzled sp=slot^(row&3) so LDS stays linear (rule #21)
  const int c0=(w*2+0)*64+lane, c1=c0+64;
  const int r0=c0>>2, sp0=(c0&3)^(r0&3);
  const int r1=c1>>2, sp1=(c1&3)^(r1&3);
  u16* lA0 = sAh + (w*2+0)*512; u16* lA1 = sAh + (w*2+1)*512;
  u16* lB0 = sBh + (w*2+0)*512; u16* lB1 = sBh + (w*2+1)*512;
  const u16* A0 = Ah + (size_t)(m0+r0)*lda + sp0*8;
  const u16* A1 = Ah + (size_t)(m0+r1)*lda + sp1*8;
  const u16* B0 = Bh + (size_t)(n0+r0)*ldb + sp0*8;
  const u16* B1 = Bh + (size_t)(n0+r1)*ldb + sp1*8;
  const u16 *A0l=nullptr,*A1l=nullptr,*B0l=nullptr,*B1l=nullptr;
  u16 *lA0l=nullptr,*lA1l=nullptr,*lB0l=nullptr,*lB1l=nullptr;
  if constexpr(SPLIT){
    A0l = Al + (size_t)(m0+r0)*ldal + sp0*8;
    A1l = Al + (size_t)(m0+r1)*ldal + sp1*8;
    B0l = Bl + (size_t)(n0+r0)*ldb  + sp0*8;
    B1l = Bl + (size_t)(n0+r1)*ldb  + sp1*8;
    lA0l = sAl + (w*2+0)*512; lA1l = sAl + (w*2+1)*512;
    lB0l = sBl + (w*2+0)*512; lB1l = sBl + (w*2+1)*512;
  }

  // frag reads: row = base+f*16+l16, slot = hi16 ^ (row&3) = hi16 ^ (l16&3)
  const int axor = (hi16 ^ (l16&3))*8;
  const int aoff = (wm*64 + l16)*32 + axor;
  const int boff = (wn*64 + l16)*32 + axor;

  f32x4 acc[4][4];
  #pragma unroll
  for (int a=0;a<4;++a)
    #pragma unroll
    for (int b=0;b<4;++b) acc[a][b] = f32x4{0.f,0.f,0.f,0.f};

  for (int k0=0; k0<K; k0+=32){
    gload_lds16(A0+k0, lA0);
    gload_lds16(A1+k0, lA1);
    gload_lds16(B0+k0, lB0);
    gload_lds16(B1+k0, lB1);
    if constexpr(SPLIT){
      gload_lds16(A0l+k0, lA0l);
      gload_lds16(A1l+k0, lA1l);
      gload_lds16(B0l+k0, lB0l);
      gload_lds16(B1l+k0, lB1l);
    }
    __syncthreads();
    bf16x8 fa[4], fb[4], fal[4], fbl[4];
    #pragma unroll
    for (int f=0; f<4; ++f){
      fa[f] = *(const bf16x8*)&sAh[aoff + f*512];
      fb[f] = *(const bf16x8*)&sBh[boff + f*512];
      if constexpr(SPLIT){
        fal[f] = *(const bf16x8*)&sAl[aoff + f*512];
        fbl[f] = *(const bf16x8*)&sBl[boff + f*512];
      }
    }
    #pragma unroll
    for (int fm=0; fm<4; ++fm){
      #pragma unroll
      for (int fn=0; fn<4; ++fn){
        acc[fm][fn] = __builtin_amdgcn_mfma_f32_16x16x32_bf16(fa[fm], fb[fn], acc[fm][fn], 0,0,0);
        if constexpr(SPLIT){
          acc[fm][fn] = __builtin_amdgcn_mfma_f32_16x16x32_bf16(fal[fm], fb[fn],  acc[fm][fn], 0,0,0);
          acc[fm][fn] = __builtin_amdgcn_mfma_f32_16x16x32_bf16(fa[fm],  fbl[fn], acc[fm][fn], 0,0,0);
        }
      }
    }
    __syncthreads();
  }

  #pragma unroll
  for (int fm=0; fm<4; ++fm){
    int grow = m0 + wm*64 + fm*16 + hi16*4;
    #pragma unroll
    for (int fn=0; fn<4; ++fn){
      int gcol = n0 + wn*64 + fn*16 + l16;
      float bb;
      if constexpr(BIAS2) bb = (gcol>=1024) ? bias1[gcol-1024] : bias0[gcol];
      else bb = bias0[gcol];
      #pragma unroll
      for (int r2=0;r2<4;++r2){
        float v = acc[fm][fn][r2] + bb;
        if constexpr(OUTBF) Cb[(size_t)(grow+r2)*ldc + gcol] = f2bf(v);
        else                Cf[(size_t)(grow+r2)*ldc + gcol] = v;
      }
    }
  }
}

// ---------------- fixup: precise 3-pass for flagged rows (gather + VALU convert) ----------------
#define LSTR 40
__global__ __launch_bounds__(256) void gemm_fix(
    const float* __restrict__ Xs, const float* __restrict__ Hs, const float* __restrict__ Ss,
    const float* __restrict__ W0, const float* __restrict__ W1, const float* __restrict__ W2,
    const float* __restrict__ b0, const float* __restrict__ b1, const float* __restrict__ b2,
    const int* __restrict__ cr, float* __restrict__ C)
{
  const int count = cr[0];
  const int m0 = blockIdx.y * 128;
  if (m0 >= count) return;
  const int* rows = cr + 1;

  __shared__ u16 sAh[128*LSTR];
  __shared__ u16 sAl[128*LSTR];
  __shared__ u16 sBh[128*LSTR];
  __shared__ u16 sBl[128*LSTR];

  const int tid = threadIdx.x;
  const int n0 = blockIdx.x * 128;
  int seg = n0 >> 10;
  const float* W    = (seg==0) ? W0 : (seg==1 ? W1 : W2);
  const float* bias = (seg==0) ? b0 : (seg==1 ? b1 : b2);
  int nw = n0 & 1023;

  const int wave = tid >> 6, lane = tid & 63;
  const int wm = wave >> 1, wn = wave & 1;
  const int l16 = lane & 15, lk8 = (lane >> 4) * 8;

  f32x4 acc[4][4];
  #pragma unroll
  for (int a=0;a<4;++a)
    #pragma unroll
    for (int b=0;b<4;++b) acc[a][b] = f32x4{0.f,0.f,0.f,0.f};

  for (int k0 = 0; k0 < 5120; k0 += 32){
    #pragma unroll
    for (int i=0;i<4;++i){
      int flat = tid + i*256;
      int r  = flat >> 3;
      int c4 = flat & 7;
      int kk = k0 + c4*4;
      int mrow = rows[min(m0 + r, count-1)];
      const float* srcA;
      if (kk < 1024)      srcA = Xs + (size_t)mrow*1024 + kk;
      else if (kk < 3072) srcA = Hs + (size_t)mrow*2048 + (kk - 1024);
      else                srcA = Ss + (size_t)mrow*2048 + (kk - 3072);
      f32x4 va = *(const f32x4*)srcA;
      f32x4 vb = *(const f32x4*)(W + (size_t)(nw + r)*5120 + kk);
      u16x4 ah, bh, al, bl;
      #pragma unroll
      for (int j=0;j<4;++j){
        u16 hA = f2bf(va[j]); ah[j] = hA; al[j] = f2bf(va[j] - bf2f(hA));
        u16 hB = f2bf(vb[j]); bh[j] = hB; bl[j] = f2bf(vb[j] - bf2f(hB));
      }
      int o = r*LSTR + c4*4;
      *(u16x4*)&sAh[o] = ah;
      *(u16x4*)&sBh[o] = bh;
      *(u16x4*)&sAl[o] = al;
      *(u16x4*)&sBl[o] = bl;
    }
    __syncthreads();
    bf16x8 fah[4], fbh[4], fal[4], fbl[4];
    #pragma unroll
    for (int f=0; f<4; ++f){
      int ra  = (wm*64 + f*16 + l16)*LSTR + lk8;
      int rb2 = (wn*64 + f*16 + l16)*LSTR + lk8;
      fah[f] = *(const bf16x8*)&sAh[ra];
      fbh[f] = *(const bf16x8*)&sBh[rb2];
      fal[f] = *(const bf16x8*)&sAl[ra];
      fbl[f] = *(const bf16x8*)&sBl[rb2];
    }
    #pragma unroll
    for (int fm=0; fm<4; ++fm){
      #pragma unroll
      for (int fn=0; fn<4; ++fn){
        acc[fm][fn] = __builtin_amdgcn_mfma_f32_16x16x32_bf16(fah[fm], fbh[fn], acc[fm][fn], 0,0,0);
        acc[fm][fn] = __builtin_amdgcn_mfma_f32_16x16x32_bf16(fal[fm], fbh[fn], acc[fm][fn], 0,0,0);
        acc[fm][fn] = __builtin_amdgcn_mfma_f32_16x16x32_bf16(fah[fm], fbl[fn], acc[fm][fn], 0,0,0);
      }
    }
    __syncthreads();
  }

  #pragma unroll
  for (int fm=0; fm<4; ++fm){
    int trow = wm*64 + fm*16 + (lane>>4)*4;
    #pragma unroll
    for (int fn=0; fn<4; ++fn){
      int lcol = wn*64 + fn*16 + l16;
      float bb = bias[nw + lcol];
      #pragma unroll
      for (int r2=0;r2<4;++r2){
        int mrow = rows[min(m0 + trow + r2, count-1)];
        C[(size_t)mrow*3072 + (n0 + lcol)] = acc[fm][fn][r2] + bb;
      }
    }
  }
}

// ---------------- epilogue ----------------
__global__ __launch_bounds__(256) void epilogue(
    const float* __restrict__ rawfio, const u16* __restrict__ rawg,
    const float* __restrict__ c_prev, const float* __restrict__ d_prev,
    const float* __restrict__ b_prev, const float* __restrict__ theta,
    float* __restrict__ out)
{
  const int b = blockIdx.x;
  const int tid = threadIdx.x;
  float* Hout = out;
  float* Cout = out + (size_t)8388608;
  float* Dout = out + (size_t)16777216;
  float* Bout = out + (size_t)25165824;
  const float bp = b_prev[b];
  const float inv_t = 1.0f / (2.0f*bp + 1e-4f);
  float conv_acc = 0.f, emer_acc = 0.f;
  const size_t rb3 = (size_t)b*3072;
  const size_t rg = (size_t)b*2048;
  const float p23 = (float)(2.0/3.0);

  #pragma unroll
  for (int j=0;j<4;++j){
    int h = tid + j*256;
    float fr = rawfio[rb3 + h];
    float ir = rawfio[rb3 + 1024 + h];
    float og = rawfio[rb3 + 2048 + h];
    float g0 = bf2f(rawg[rg + h]);
    float g1 = bf2f(rawg[rg + 1024 + h]);

    float mx = fmaxf(fr, fmaxf(ir, og));
    float ef = expf((fr-mx)*inv_t);
    float ei = expf((ir-mx)*inv_t);
    float eo = expf((og-mx)*inv_t);
    float inv_s = 1.0f/(ef+ei+eo);
    float ft = ef*inv_s, it = ei*inv_s, ot = eo*inv_s;

    f32x2 cp = *(const f32x2*)(c_prev + 2*((size_t)b*1024 + h));
    f32x2 dp = *(const f32x2*)(d_prev + 2*((size_t)b*1024 + h));

    float r0 = (1.f-ft)*cp[0], r1 = (1.f-ft)*cp[1];
    float rm2 = r0*r0 + r1*r1 + 1e-8f;
    conv_acc += rm2;
    float rmag = sqrtf(rm2);
    float mm = fmaxf(rmag, 1e-8f);
    float cm = powf(mm, p23);
    float ph = atan2f(r1, r0 + 1e-10f);
    float comp0 = fminf(fmaxf(cm * cosf(ph), -10.f), 10.f);
    float comp1 = fminf(fmaxf(cm * sinf(ph), -10.f), 10.f);

    float d0 = dp[0] + 0.01f*comp0;
    float d1 = dp[1] + 0.01f*comp1;
    float dmn = sqrtf(d0*d0 + d1*d1 + 1e-8f);
    if (dmn > 20.f){ float sc = 20.f/dmn; d0*=sc; d1*=sc; }

    float gt0 = tanhf(g0), gt1 = tanhf(g1);
    float cu0 = ft*cp[0] + it*gt0;
    float cu1 = ft*cp[1] + it*gt1;
    float th = theta[h];
    float cth = cosf(th), sth = sinf(th);
    float c0 = cth*cu0 - sth*cu1;
    float c1 = sth*cu0 + cth*cu1;
    float cs0 = tanhf(c0), cs1 = tanhf(c1);
    float hr0 = ot*cs0, hr1 = ot*cs1;

    float pa = atan2f(hr1, hr0 + 1e-10f);
    float pb2 = atan2f(d1, d0 + 1e-10f);
    float cg = cosf((pa - pb2)*0.5f);
    float G = cg*cg;
    float h0 = G*hr0, h1 = G*hr1;
    emer_acc += h0*h0 + h1*h1 + 1e-8f;

    h0 = (h0==h0)?h0:0.f;  h1 = (h1==h1)?h1:0.f;
    c0 = (c0==c0)?c0:0.f;  c1 = (c1==c1)?c1:0.f;
    d0 = (d0==d0)?d0:0.f;  d1 = (d1==d1)?d1:0.f;

    size_t oi = 2*((size_t)b*1024 + h);
    *(f32x2*)(Hout+oi) = f32x2{h0,h1};
    *(f32x2*)(Cout+oi) = f32x2{c0,c1};
    *(f32x2*)(Dout+oi) = f32x2{d0,d1};
  }

  #pragma unroll
  for (int off=32; off; off>>=1){
    conv_acc += __shfl_down(conv_acc, off);
    emer_acc += __shfl_down(emer_acc, off);
  }
  __shared__ float sred[8];
  int wv = tid>>6, ln = tid&63;
  if (ln==0){ sred[wv]=conv_acc; sred[4+wv]=emer_acc; }
  __syncthreads();
  if (tid==0){
    float cv = sred[0]+sred[1]+sred[2]+sred[3];
    float em = sred[4]+sred[5]+sred[6]+sred[7];
    float bm = cv/(cv+em+1e-8f);
    float bt = 0.99f*bp + 0.01f*bm;
    bt = (bt==bt)?bt:0.5f;
    Bout[b] = bt;
  }
}

extern "C" void kernel_launch(void* const* d_in, const int* in_sizes, int n_in,
                              void* d_out, int out_size, void* d_ws, size_t ws_size,
                              hipStream_t stream)
{
  const float* x_t    = (const float*)d_in[0];
  const float* h_prev = (const float*)d_in[1];
  const float* c_prev = (const float*)d_in[2];
  const float* d_prev = (const float*)d_in[3];
  const float* b_prev = (const float*)d_in[4];
  const float* Wf_w   = (const float*)d_in[5];
  const float* Wf_b   = (const float*)d_in[6];
  const float* Wi_w   = (const float*)d_in[7];
  const float* Wi_b   = (const float*)d_in[8];
  const float* Wo_w   = (const float*)d_in[9];
  const float* Wo_b   = (const float*)d_in[10];
  const float* Wc_w   = (const float*)d_in[11];
  const float* Wc_b   = (const float*)d_in[12];
  const float* Wr_w   = (const float*)d_in[13];
  const float* Wr_b   = (const float*)d_in[14];
  const float* theta  = (const float*)d_in[15];

  char* W = (char*)d_ws;
  // region 0: raw_fio f32 [4096][3072] (50331648 B); xc f32 [4096][2048] aliased (dead before fio writes)
  float* rawfio = (float*)W;
  float* xc     = (float*)W;
  // region 1: surf f32 [4096][2048] (33554432 B); pre-GEMM1 aliases Wr_hi/Wr_lo/x_lo; post-fixup alias raw_g bf16
  float* surf   = (float*)(W + 50331648);
  u16*   Wr_hi  = (u16*)(W + 50331648);
  u16*   Wr_lo  = (u16*)(W + 50331648 + 4194304);
  u16*   x_lo   = (u16*)(W + 50331648 + 8388608);
  u16*   raw_g  = (u16*)(W + 50331648);
  // region 2: cA_hi bf16 [4096][5120] (41943040 B)
  u16*   cA     = (u16*)(W + 83886080);
  // region 3: WD bf16 weight staging [2048][5120] (20971520 B)
  u16*   WD     = (u16*)(W + 125829120);
  // region 4: idx: [0]=count, [1..4096]=rows
  int*   idx    = (int*)(W + 146800640);

  dim3 blk(256);

  // 1. x,h -> cA_hi[:,0:3072] + x_lo
  cvt_xh<<<dim3(3,4096), blk, 0, stream>>>(x_t, h_prev, cA, x_lo);
  // 2. Wr -> hi/lo
  cvt_hilo<<<2048, blk, 0, stream>>>(Wr_w, Wr_hi, Wr_lo, 524288);
  // 3. GEMM1 (split 3-pass): xc = x @ Wr^T + b
  gemm_fast<true,false,false><<<dim3(16,32), blk, 0, stream>>>(
      cA, 5120, x_lo, 1024, Wr_hi, 1024, Wr_lo,
      Wr_b, nullptr, xc, nullptr, 2048, 1024);
  // 4. surfaced -> surf f32 + cA_hi[:,3072:5120]
  prep_surf<<<16384, blk, 0, stream>>>(xc, d_prev, surf, cA);
  // 5. flag low-temperature rows
  flag_rows<<<1, blk, 0, stream>>>(b_prev, idx);
  // 6. Wf,Wi -> WD
  cvt_hi<<<5120, blk, 0, stream>>>(Wf_w, WD, 1310720);
  cvt_hi<<<5120, blk, 0, stream>>>(Wi_w, WD + (size_t)1024*5120, 1310720);
  // 7. f,i raw (1-pass)
  gemm_fast<false,false,true><<<dim3(16,32), blk, 0, stream>>>(
      cA, 5120, nullptr, 0, WD, 5120, nullptr,
      Wf_b, Wi_b, rawfio, nullptr, 3072, 5120);
  // 8. Wo -> WD
  cvt_hi<<<5120, blk, 0, stream>>>(Wo_w, WD, 1310720);
  // 9. o raw (1-pass)
  gemm_fast<false,false,false><<<dim3(8,32), blk, 0, stream>>>(
      cA, 5120, nullptr, 0, WD, 5120, nullptr,
      Wo_b, nullptr, rawfio + 2048, nullptr, 3072, 5120);
  // 10. fixup flagged rows (precise 3-pass)
  gemm_fix<<<dim3(24,32), blk, 0, stream>>>(
      x_t, h_prev, surf, Wf_w, Wi_w, Wo_w, Wf_b, Wi_b, Wo_b, idx, rawfio);
  // 11. Wc -> WD
  cvt_hi<<<10240, blk, 0, stream>>>(Wc_w, WD, 2621440);
  // 12. g raw (1-pass, bf16 out, overwrites surf region)
  gemm_fast<false,true,false><<<dim3(16,32), blk, 0, stream>>>(
      cA, 5120, nullptr, 0, WD, 5120, nullptr,
      Wc_b, nullptr, nullptr, raw_g, 2048, 5120);
  // 13. epilogue
  epilogue<<<4096, blk, 0, stream>>>(rawfio, raw_g, c_prev, d_prev, b_prev, theta, (float*)d_out);
}

// Round 3
// 666.185 us; speedup vs baseline: 2.3384x; 1.5692x over previous
//
#include <hip/hip_runtime.h>
#include <math.h>

typedef unsigned short u16;
typedef unsigned int u32;
typedef u16 u16x4 __attribute__((ext_vector_type(4)));
typedef float f32x2 __attribute__((ext_vector_type(2)));
typedef float f32x4 __attribute__((ext_vector_type(4)));
typedef __bf16 bf16x8 __attribute__((ext_vector_type(8)));

__device__ __forceinline__ u16 f2bf(float f){
  u32 u = __builtin_bit_cast(u32, f);
  u32 r = u + 0x7FFFu + ((u >> 16) & 1u);
  return (u16)(r >> 16);
}
__device__ __forceinline__ float bf2f(u16 h){
  u32 u = ((u32)h) << 16;
  return __builtin_bit_cast(float, u);
}

typedef __attribute__((address_space(1))) const unsigned int gas_u32;
typedef __attribute__((address_space(3))) unsigned int las_u32;
__device__ __forceinline__ void gload_lds16(const void* g, void* l){
  __builtin_amdgcn_global_load_lds((gas_u32*)g, (las_u32*)l, 16, 0, 0);
}

// ---------------- converts ----------------
__global__ __launch_bounds__(256) void cvt_hi(const float* __restrict__ in, u16* __restrict__ out, int n4){
  int i = blockIdx.x*256 + threadIdx.x;
  if (i >= n4) return;
  f32x4 v = *(const f32x4*)(in + (size_t)i*4);
  u16x4 o;
  #pragma unroll
  for (int j=0;j<4;++j) o[j]=f2bf(v[j]);
  *(u16x4*)(out + (size_t)i*4) = o;
}

__global__ __launch_bounds__(256) void cvt_hilo(const float* __restrict__ in, u16* __restrict__ hi, u16* __restrict__ lo, int n4){
  int i = blockIdx.x*256 + threadIdx.x;
  if (i >= n4) return;
  f32x4 v = *(const f32x4*)(in + (size_t)i*4);
  u16x4 oh, ol;
  #pragma unroll
  for (int j=0;j<4;++j){ u16 h=f2bf(v[j]); oh[j]=h; ol[j]=f2bf(v[j]-bf2f(h)); }
  *(u16x4*)(hi + (size_t)i*4) = oh;
  *(u16x4*)(lo + (size_t)i*4) = ol;
}

// x,h -> cA_hi[:,0:3072] (bf16), x also -> x_lo
__global__ __launch_bounds__(256) void cvt_xh(const float* __restrict__ x, const float* __restrict__ h,
                                              u16* __restrict__ cA, u16* __restrict__ xlo){
  int b = blockIdx.y;
  int c0 = (blockIdx.x*256 + threadIdx.x)*4;  // grid.x=3 -> c0 in [0,3072)
  f32x4 v;
  if (c0 < 1024) v = *(const f32x4*)(x + (size_t)b*1024 + c0);
  else           v = *(const f32x4*)(h + (size_t)b*2048 + (c0-1024));
  u16x4 hi4;
  #pragma unroll
  for (int j=0;j<4;++j) hi4[j]=f2bf(v[j]);
  *(u16x4*)(cA + (size_t)b*5120 + c0) = hi4;
  if (c0 < 1024){
    u16x4 lo4;
    #pragma unroll
    for (int j=0;j<4;++j) lo4[j]=f2bf(v[j]-bf2f(hi4[j]));
    *(u16x4*)(xlo + (size_t)b*1024 + c0) = lo4;
  }
}

// surfaced: f32 buffer + bf16 into cA_hi[:,3072:5120]
__global__ __launch_bounds__(256) void prep_surf(const float* __restrict__ xc, const float* __restrict__ dp,
                                                 float* __restrict__ surf, u16* __restrict__ cA){
  int i = blockIdx.x*256 + threadIdx.x;   // over 4096*1024
  int b = i >> 10, h = i & 1023;
  f32x2 z = *(const f32x2*)(xc + 2*(size_t)i);
  f32x2 d = *(const f32x2*)(dp + 2*(size_t)i);
  float pa = atan2f(z[1], z[0] + 1e-10f);
  float pb = atan2f(d[1], d[0] + 1e-10f);
  float cc = cosf((pa - pb)*0.5f);
  float T = cc*cc;
  float dmag = sqrtf(d[0]*d[0] + d[1]*d[1] + 1e-8f);
  float dscale = sqrtf(fminf(fmaxf(dmag, 1e-6f), 20.0f));
  float s = T * dscale / (dmag + 1e-8f);
  float o0 = d[0]*s, o1 = d[1]*s;
  *(f32x2*)(surf + 2*(size_t)i) = f32x2{o0, o1};
  u32 pk = (u32)f2bf(o0) | ((u32)f2bf(o1) << 16);
  *(u32*)&cA[(size_t)b*5120 + 3072 + 2*h] = pk;
}

// rows with small temperature -> need precise raws. out[0]=count, out[1..]=rows; mask[b] flag
__global__ __launch_bounds__(256) void flag_rows(const float* __restrict__ bp, int* __restrict__ out,
                                                 char* __restrict__ mask){
  __shared__ int cnt;
  if (threadIdx.x==0) cnt=0;
  __syncthreads();
  for (int i=threadIdx.x; i<4096; i+=256){
    bool f = bp[i] < 0.04f;
    mask[i] = f ? 1 : 0;
    if (f){ int p = atomicAdd(&cnt,1); out[1+p]=i; }
  }
  __syncthreads();
  if (threadIdx.x==0) out[0]=cnt;
}

// write bias into rawfio rows that will be re-accumulated by split-K fixup
__global__ __launch_bounds__(256) void fix_init(const char* __restrict__ mask,
    const float* __restrict__ b0, const float* __restrict__ b1, const float* __restrict__ b2,
    float* __restrict__ C){
  int b = blockIdx.x;
  if (!mask[b]) return;
  #pragma unroll
  for (int j0=0; j0<3072; j0+=256){
    int j = j0 + threadIdx.x;
    float bb = (j<1024) ? b0[j] : ((j<2048) ? b1[j-1024] : b2[j-2048]);
    C[(size_t)b*3072 + j] = bb;
  }
}

// ---------------- fast pure-bf16 GEMM (m97 structure + 4-way swizzle) ----------------
// C[m][n] = sum_k A[m][k]*B[n][k] + bias(n).  SPLIT: 3-pass hi/lo.
template<bool SPLIT, bool OUTBF, bool BIAS2>
__global__ __launch_bounds__(256) void gemm_fast(
    const u16* __restrict__ Ah, int lda,
    const u16* __restrict__ Al, int ldal,
    const u16* __restrict__ Bh, int ldb,
    const u16* __restrict__ Bl,
    const float* __restrict__ bias0, const float* __restrict__ bias1,
    float* __restrict__ Cf, u16* __restrict__ Cb, int ldc, int K)
{
  __shared__ u16 sAh[128*32];
  __shared__ u16 sBh[128*32];
  __shared__ u16 sAl[SPLIT?128*32:8];
  __shared__ u16 sBl[SPLIT?128*32:8];

  const int tid=threadIdx.x, lane=tid&63, w=tid>>6;
  const int m0=blockIdx.y*128, n0=blockIdx.x*128;
  const int wm=w>>1, wn=w&1, l16=lane&15, hi16=lane>>4;

  const int c0=(w*2+0)*64+lane, c1=c0+64;
  const int r0=c0>>2, sp0=(c0&3)^(r0&3);
  const int r1=c1>>2, sp1=(c1&3)^(r1&3);
  u16* lA0 = sAh + (w*2+0)*512; u16* lA1 = sAh + (w*2+1)*512;
  u16* lB0 = sBh + (w*2+0)*512; u16* lB1 = sBh + (w*2+1)*512;
  const u16* A0 = Ah + (size_t)(m0+r0)*lda + sp0*8;
  const u16* A1 = Ah + (size_t)(m0+r1)*lda + sp1*8;
  const u16* B0 = Bh + (size_t)(n0+r0)*ldb + sp0*8;
  const u16* B1 = Bh + (size_t)(n0+r1)*ldb + sp1*8;
  const u16 *A0l=nullptr,*A1l=nullptr,*B0l=nullptr,*B1l=nullptr;
  u16 *lA0l=nullptr,*lA1l=nullptr,*lB0l=nullptr,*lB1l=nullptr;
  if constexpr(SPLIT){
    A0l = Al + (size_t)(m0+r0)*ldal + sp0*8;
    A1l = Al + (size_t)(m0+r1)*ldal + sp1*8;
    B0l = Bl + (size_t)(n0+r0)*ldb  + sp0*8;
    B1l = Bl + (size_t)(n0+r1)*ldb  + sp1*8;
    lA0l = sAl + (w*2+0)*512; lA1l = sAl + (w*2+1)*512;
    lB0l = sBl + (w*2+0)*512; lB1l = sBl + (w*2+1)*512;
  }

  const int axor = (hi16 ^ (l16&3))*8;
  const int aoff = (wm*64 + l16)*32 + axor;
  const int boff = (wn*64 + l16)*32 + axor;

  f32x4 acc[4][4];
  #pragma unroll
  for (int a=0;a<4;++a)
    #pragma unroll
    for (int b=0;b<4;++b) acc[a][b] = f32x4{0.f,0.f,0.f,0.f};

  for (int k0=0; k0<K; k0+=32){
    gload_lds16(A0+k0, lA0);
    gload_lds16(A1+k0, lA1);
    gload_lds16(B0+k0, lB0);
    gload_lds16(B1+k0, lB1);
    if constexpr(SPLIT){
      gload_lds16(A0l+k0, lA0l);
      gload_lds16(A1l+k0, lA1l);
      gload_lds16(B0l+k0, lB0l);
      gload_lds16(B1l+k0, lB1l);
    }
    __syncthreads();
    bf16x8 fa[4], fb[4], fal[4], fbl[4];
    #pragma unroll
    for (int f=0; f<4; ++f){
      fa[f] = *(const bf16x8*)&sAh[aoff + f*512];
      fb[f] = *(const bf16x8*)&sBh[boff + f*512];
      if constexpr(SPLIT){
        fal[f] = *(const bf16x8*)&sAl[aoff + f*512];
        fbl[f] = *(const bf16x8*)&sBl[boff + f*512];
      }
    }
    #pragma unroll
    for (int fm=0; fm<4; ++fm){
      #pragma unroll
      for (int fn=0; fn<4; ++fn){
        acc[fm][fn] = __builtin_amdgcn_mfma_f32_16x16x32_bf16(fa[fm], fb[fn], acc[fm][fn], 0,0,0);
        if constexpr(SPLIT){
          acc[fm][fn] = __builtin_amdgcn_mfma_f32_16x16x32_bf16(fal[fm], fb[fn],  acc[fm][fn], 0,0,0);
          acc[fm][fn] = __builtin_amdgcn_mfma_f32_16x16x32_bf16(fa[fm],  fbl[fn], acc[fm][fn], 0,0,0);
        }
      }
    }
    __syncthreads();
  }

  #pragma unroll
  for (int fm=0; fm<4; ++fm){
    int grow = m0 + wm*64 + fm*16 + hi16*4;
    #pragma unroll
    for (int fn=0; fn<4; ++fn){
      int gcol = n0 + wn*64 + fn*16 + l16;
      float bb;
      if constexpr(BIAS2) bb = (gcol>=1024) ? bias1[gcol-1024] : bias0[gcol];
      else bb = bias0[gcol];
      #pragma unroll
      for (int r2=0;r2<4;++r2){
        float v = acc[fm][fn][r2] + bb;
        if constexpr(OUTBF) Cb[(size_t)(grow+r2)*ldc + gcol] = f2bf(v);
        else                Cf[(size_t)(grow+r2)*ldc + gcol] = v;
      }
    }
  }
}

// ---------------- fixup: precise 3-pass for flagged rows, SPLIT-K (8 chunks of 640) ----------------
// Accumulates into C via atomicAdd (bias pre-written by fix_init).
#define LSTR 40
#define FIX_KC 8
#define FIX_KLEN 640
__global__ __launch_bounds__(256) void gemm_fix_sk(
    const float* __restrict__ Xs, const float* __restrict__ Hs, const float* __restrict__ Ss,
    const float* __restrict__ W0, const float* __restrict__ W1, const float* __restrict__ W2,
    const int* __restrict__ cr, float* __restrict__ C)
{
  const int count = cr[0];
  const int m0 = blockIdx.y * 128;
  if (m0 >= count) return;
  const int* rows = cr + 1;
  const int kbeg = blockIdx.z * FIX_KLEN;
  const int kend = kbeg + FIX_KLEN;

  __shared__ u16 sAh[128*LSTR];
  __shared__ u16 sAl[128*LSTR];
  __shared__ u16 sBh[128*LSTR];
  __shared__ u16 sBl[128*LSTR];

  const int tid = threadIdx.x;
  const int n0 = blockIdx.x * 128;
  int seg = n0 >> 10;
  const float* W = (seg==0) ? W0 : (seg==1 ? W1 : W2);
  int nw = n0 & 1023;

  const int wave = tid >> 6, lane = tid & 63;
  const int wm = wave >> 1, wn = wave & 1;
  const int l16 = lane & 15, lk8 = (lane >> 4) * 8;

  f32x4 acc[4][4];
  #pragma unroll
  for (int a=0;a<4;++a)
    #pragma unroll
    for (int b=0;b<4;++b) acc[a][b] = f32x4{0.f,0.f,0.f,0.f};

  for (int k0 = kbeg; k0 < kend; k0 += 32){
    #pragma unroll
    for (int i=0;i<4;++i){
      int flat = tid + i*256;
      int r  = flat >> 3;
      int c4 = flat & 7;
      int kk = k0 + c4*4;
      int mrow = rows[min(m0 + r, count-1)];
      const float* srcA;
      if (kk < 1024)      srcA = Xs + (size_t)mrow*1024 + kk;
      else if (kk < 3072) srcA = Hs + (size_t)mrow*2048 + (kk - 1024);
      else                srcA = Ss + (size_t)mrow*2048 + (kk - 3072);
      f32x4 va = *(const f32x4*)srcA;
      f32x4 vb = *(const f32x4*)(W + (size_t)(nw + r)*5120 + kk);
      u16x4 ah, bh, al, bl;
      #pragma unroll
      for (int j=0;j<4;++j){
        u16 hA = f2bf(va[j]); ah[j] = hA; al[j] = f2bf(va[j] - bf2f(hA));
        u16 hB = f2bf(vb[j]); bh[j] = hB; bl[j] = f2bf(vb[j] - bf2f(hB));
      }
      int o = r*LSTR + c4*4;
      *(u16x4*)&sAh[o] = ah;
      *(u16x4*)&sBh[o] = bh;
      *(u16x4*)&sAl[o] = al;
      *(u16x4*)&sBl[o] = bl;
    }
    __syncthreads();
    bf16x8 fah[4], fbh[4], fal[4], fbl[4];
    #pragma unroll
    for (int f=0; f<4; ++f){
      int ra  = (wm*64 + f*16 + l16)*LSTR + lk8;
      int rb2 = (wn*64 + f*16 + l16)*LSTR + lk8;
      fah[f] = *(const bf16x8*)&sAh[ra];
      fbh[f] = *(const bf16x8*)&sBh[rb2];
      fal[f] = *(const bf16x8*)&sAl[ra];
      fbl[f] = *(const bf16x8*)&sBl[rb2];
    }
    #pragma unroll
    for (int fm=0; fm<4; ++fm){
      #pragma unroll
      for (int fn=0; fn<4; ++fn){
        acc[fm][fn] = __builtin_amdgcn_mfma_f32_16x16x32_bf16(fah[fm], fbh[fn], acc[fm][fn], 0,0,0);
        acc[fm][fn] = __builtin_amdgcn_mfma_f32_16x16x32_bf16(fal[fm], fbh[fn], acc[fm][fn], 0,0,0);
        acc[fm][fn] = __builtin_amdgcn_mfma_f32_16x16x32_bf16(fah[fm], fbl[fn], acc[fm][fn], 0,0,0);
      }
    }
    __syncthreads();
  }

  #pragma unroll
  for (int fm=0; fm<4; ++fm){
    int trow = wm*64 + fm*16 + (lane>>4)*4;
    #pragma unroll
    for (int fn=0; fn<4; ++fn){
      int lcol = wn*64 + fn*16 + l16;
      #pragma unroll
      for (int r2=0;r2<4;++r2){
        int mi = m0 + trow + r2;
        if (mi < count){
          int mrow = rows[mi];
          atomicAdd(&C[(size_t)mrow*3072 + (n0 + lcol)], acc[fm][fn][r2]);
        }
      }
    }
  }
}

// ---------------- epilogue ----------------
__global__ __launch_bounds__(256) void epilogue(
    const float* __restrict__ rawfio, const u16* __restrict__ rawg,
    const float* __restrict__ c_prev, const float* __restrict__ d_prev,
    const float* __restrict__ b_prev, const float* __restrict__ theta,
    float* __restrict__ out)
{
  const int b = blockIdx.x;
  const int tid = threadIdx.x;
  float* Hout = out;
  float* Cout = out + (size_t)8388608;
  float* Dout = out + (size_t)16777216;
  float* Bout = out + (size_t)25165824;
  const float bp = b_prev[b];
  const float inv_t = 1.0f / (2.0f*bp + 1e-4f);
  float conv_acc = 0.f, emer_acc = 0.f;
  const size_t rb3 = (size_t)b*3072;
  const size_t rg = (size_t)b*2048;
  const float p23 = (float)(2.0/3.0);

  #pragma unroll
  for (int j=0;j<4;++j){
    int h = tid + j*256;
    float fr = rawfio[rb3 + h];
    float ir = rawfio[rb3 + 1024 + h];
    float og = rawfio[rb3 + 2048 + h];
    float g0 = bf2f(rawg[rg + h]);
    float g1 = bf2f(rawg[rg + 1024 + h]);

    float mx = fmaxf(fr, fmaxf(ir, og));
    float ef = expf((fr-mx)*inv_t);
    float ei = expf((ir-mx)*inv_t);
    float eo = expf((og-mx)*inv_t);
    float inv_s = 1.0f/(ef+ei+eo);
    float ft = ef*inv_s, it = ei*inv_s, ot = eo*inv_s;

    f32x2 cp = *(const f32x2*)(c_prev + 2*((size_t)b*1024 + h));
    f32x2 dp = *(const f32x2*)(d_prev + 2*((size_t)b*1024 + h));

    float r0 = (1.f-ft)*cp[0], r1 = (1.f-ft)*cp[1];
    float rm2 = r0*r0 + r1*r1 + 1e-8f;
    conv_acc += rm2;
    float rmag = sqrtf(rm2);
    float mm = fmaxf(rmag, 1e-8f);
    float cm = powf(mm, p23);
    float ph = atan2f(r1, r0 + 1e-10f);
    float comp0 = fminf(fmaxf(cm * cosf(ph), -10.f), 10.f);
    float comp1 = fminf(fmaxf(cm * sinf(ph), -10.f), 10.f);

    float d0 = dp[0] + 0.01f*comp0;
    float d1 = dp[1] + 0.01f*comp1;
    float dmn = sqrtf(d0*d0 + d1*d1 + 1e-8f);
    if (dmn > 20.f){ float sc = 20.f/dmn; d0*=sc; d1*=sc; }

    float gt0 = tanhf(g0), gt1 = tanhf(g1);
    float cu0 = ft*cp[0] + it*gt0;
    float cu1 = ft*cp[1] + it*gt1;
    float th = theta[h];
    float cth = cosf(th), sth = sinf(th);
    float c0 = cth*cu0 - sth*cu1;
    float c1 = sth*cu0 + cth*cu1;
    float cs0 = tanhf(c0), cs1 = tanhf(c1);
    float hr0 = ot*cs0, hr1 = ot*cs1;

    float pa = atan2f(hr1, hr0 + 1e-10f);
    float pb2 = atan2f(d1, d0 + 1e-10f);
    float cg = cosf((pa - pb2)*0.5f);
    float G = cg*cg;
    float h0 = G*hr0, h1 = G*hr1;
    emer_acc += h0*h0 + h1*h1 + 1e-8f;

    h0 = (h0==h0)?h0:0.f;  h1 = (h1==h1)?h1:0.f;
    c0 = (c0==c0)?c0:0.f;  c1 = (c1==c1)?c1:0.f;
    d0 = (d0==d0)?d0:0.f;  d1 = (d1==d1)?d1:0.f;

    size_t oi = 2*((size_t)b*1024 + h);
    *(f32x2*)(Hout+oi) = f32x2{h0,h1};
    *(f32x2*)(Cout+oi) = f32x2{c0,c1};
    *(f32x2*)(Dout+oi) = f32x2{d0,d1};
  }

  #pragma unroll
  for (int off=32; off; off>>=1){
    conv_acc += __shfl_down(conv_acc, off);
    emer_acc += __shfl_down(emer_acc, off);
  }
  __shared__ float sred[8];
  int wv = tid>>6, ln = tid&63;
  if (ln==0){ sred[wv]=conv_acc; sred[4+wv]=emer_acc; }
  __syncthreads();
  if (tid==0){
    float cv = sred[0]+sred[1]+sred[2]+sred[3];
    float em = sred[4]+sred[5]+sred[6]+sred[7];
    float bm = cv/(cv+em+1e-8f);
    float bt = 0.99f*bp + 0.01f*bm;
    bt = (bt==bt)?bt:0.5f;
    Bout[b] = bt;
  }
}

extern "C" void kernel_launch(void* const* d_in, const int* in_sizes, int n_in,
                              void* d_out, int out_size, void* d_ws, size_t ws_size,
                              hipStream_t stream)
{
  const float* x_t    = (const float*)d_in[0];
  const float* h_prev = (const float*)d_in[1];
  const float* c_prev = (const float*)d_in[2];
  const float* d_prev = (const float*)d_in[3];
  const float* b_prev = (const float*)d_in[4];
  const float* Wf_w   = (const float*)d_in[5];
  const float* Wf_b   = (const float*)d_in[6];
  const float* Wi_w   = (const float*)d_in[7];
  const float* Wi_b   = (const float*)d_in[8];
  const float* Wo_w   = (const float*)d_in[9];
  const float* Wo_b   = (const float*)d_in[10];
  const float* Wc_w   = (const float*)d_in[11];
  const float* Wc_b   = (const float*)d_in[12];
  const float* Wr_w   = (const float*)d_in[13];
  const float* Wr_b   = (const float*)d_in[14];
  const float* theta  = (const float*)d_in[15];

  char* W = (char*)d_ws;
  // region 0: raw_fio f32 [4096][3072]; xc f32 [4096][2048] aliased (dead before fio writes)
  float* rawfio = (float*)W;
  float* xc     = (float*)W;
  // region 1: surf f32 [4096][2048]; pre-GEMM1 aliases Wr_hi/Wr_lo/x_lo; post-fixup alias raw_g bf16
  float* surf   = (float*)(W + 50331648);
  u16*   Wr_hi  = (u16*)(W + 50331648);
  u16*   Wr_lo  = (u16*)(W + 50331648 + 4194304);
  u16*   x_lo   = (u16*)(W + 50331648 + 8388608);
  u16*   raw_g  = (u16*)(W + 50331648);
  // region 2: cA_hi bf16 [4096][5120]
  u16*   cA     = (u16*)(W + 83886080);
  // region 3: WD bf16 weight staging [2048][5120]
  u16*   WD     = (u16*)(W + 125829120);
  // region 4: idx: [0]=count, [1..4096]=rows; then mask[4096] bytes
  int*   idx    = (int*)(W + 146800640);
  char*  mask   = (char*)(W + 146800640 + 4*4097);

  dim3 blk(256);

  // 1. x,h -> cA_hi[:,0:3072] + x_lo
  cvt_xh<<<dim3(3,4096), blk, 0, stream>>>(x_t, h_prev, cA, x_lo);
  // 2. Wr -> hi/lo
  cvt_hilo<<<2048, blk, 0, stream>>>(Wr_w, Wr_hi, Wr_lo, 524288);
  // 3. GEMM1 (split 3-pass): xc = x @ Wr^T + b
  gemm_fast<true,false,false><<<dim3(16,32), blk, 0, stream>>>(
      cA, 5120, x_lo, 1024, Wr_hi, 1024, Wr_lo,
      Wr_b, nullptr, xc, nullptr, 2048, 1024);
  // 4. surfaced -> surf f32 + cA_hi[:,3072:5120]
  prep_surf<<<16384, blk, 0, stream>>>(xc, d_prev, surf, cA);
  // 5. flag low-temperature rows (+ mask)
  flag_rows<<<1, blk, 0, stream>>>(b_prev, idx, mask);
  // 6. Wf,Wi -> WD
  cvt_hi<<<5120, blk, 0, stream>>>(Wf_w, WD, 1310720);
  cvt_hi<<<5120, blk, 0, stream>>>(Wi_w, WD + (size_t)1024*5120, 1310720);
  // 7. f,i raw (1-pass)
  gemm_fast<false,false,true><<<dim3(16,32), blk, 0, stream>>>(
      cA, 5120, nullptr, 0, WD, 5120, nullptr,
      Wf_b, Wi_b, rawfio, nullptr, 3072, 5120);
  // 8. Wo -> WD
  cvt_hi<<<5120, blk, 0, stream>>>(Wo_w, WD, 1310720);
  // 9. o raw (1-pass)
  gemm_fast<false,false,false><<<dim3(8,32), blk, 0, stream>>>(
      cA, 5120, nullptr, 0, WD, 5120, nullptr,
      Wo_b, nullptr, rawfio + 2048, nullptr, 3072, 5120);
  // 10a. bias-init flagged rows
  fix_init<<<4096, blk, 0, stream>>>(mask, Wf_b, Wi_b, Wo_b, rawfio);
  // 10b. split-K precise fixup (atomicAdd accumulate)
  gemm_fix_sk<<<dim3(24,32,FIX_KC), blk, 0, stream>>>(
      x_t, h_prev, surf, Wf_w, Wi_w, Wo_w, idx, rawfio);
  // 11. Wc -> WD
  cvt_hi<<<10240, blk, 0, stream>>>(Wc_w, WD, 2621440);
  // 12. g raw (1-pass, bf16 out, overwrites surf region)
  gemm_fast<false,true,false><<<dim3(16,32), blk, 0, stream>>>(
      cA, 5120, nullptr, 0, WD, 5120, nullptr,
      Wc_b, nullptr, nullptr, raw_g, 2048, 5120);
  // 13. epilogue
  epilogue<<<4096, blk, 0, stream>>>(rawfio, raw_g, c_prev, d_prev, b_prev, theta, (float*)d_out);
}

// Round 4
// 571.503 us; speedup vs baseline: 2.7258x; 1.1657x over previous
//
#include <hip/hip_runtime.h>
#include <math.h>

typedef unsigned short u16;
typedef unsigned int u32;
typedef u16 u16x4 __attribute__((ext_vector_type(4)));
typedef float f32x2 __attribute__((ext_vector_type(2)));
typedef float f32x4 __attribute__((ext_vector_type(4)));
typedef __bf16 bf16x8 __attribute__((ext_vector_type(8)));

__device__ __forceinline__ u16 f2bf(float f){
  u32 u = __builtin_bit_cast(u32, f);
  u32 r = u + 0x7FFFu + ((u >> 16) & 1u);
  return (u16)(r >> 16);
}
__device__ __forceinline__ float bf2f(u16 h){
  u32 u = ((u32)h) << 16;
  return __builtin_bit_cast(float, u);
}
__device__ __forceinline__ float ftanh(float x){
  float e = __expf(2.f*x);
  return 1.f - 2.f/(e+1.f);
}

typedef __attribute__((address_space(1))) const unsigned int gas_u32;
typedef __attribute__((address_space(3))) unsigned int las_u32;
__device__ __forceinline__ void gload_lds16(const void* g, void* l){
  __builtin_amdgcn_global_load_lds((gas_u32*)g, (las_u32*)l, 16, 0, 0);
}

// ---------------- converts ----------------
__global__ __launch_bounds__(256) void cvt_hi(const float* __restrict__ in, u16* __restrict__ out, int n4){
  int i = blockIdx.x*256 + threadIdx.x;
  if (i >= n4) return;
  f32x4 v = *(const f32x4*)(in + (size_t)i*4);
  u16x4 o;
  #pragma unroll
  for (int j=0;j<4;++j) o[j]=f2bf(v[j]);
  *(u16x4*)(out + (size_t)i*4) = o;
}

__global__ __launch_bounds__(256) void cvt_hilo(const float* __restrict__ in, u16* __restrict__ hi, u16* __restrict__ lo, int n4){
  int i = blockIdx.x*256 + threadIdx.x;
  if (i >= n4) return;
  f32x4 v = *(const f32x4*)(in + (size_t)i*4);
  u16x4 oh, ol;
  #pragma unroll
  for (int j=0;j<4;++j){ u16 h=f2bf(v[j]); oh[j]=h; ol[j]=f2bf(v[j]-bf2f(h)); }
  *(u16x4*)(hi + (size_t)i*4) = oh;
  *(u16x4*)(lo + (size_t)i*4) = ol;
}

// x,h -> cA_hi[:,0:3072] (bf16), x also -> x_lo
__global__ __launch_bounds__(256) void cvt_xh(const float* __restrict__ x, const float* __restrict__ h,
                                              u16* __restrict__ cA, u16* __restrict__ xlo){
  int b = blockIdx.y;
  int c0 = (blockIdx.x*256 + threadIdx.x)*4;
  f32x4 v;
  if (c0 < 1024) v = *(const f32x4*)(x + (size_t)b*1024 + c0);
  else           v = *(const f32x4*)(h + (size_t)b*2048 + (c0-1024));
  u16x4 hi4;
  #pragma unroll
  for (int j=0;j<4;++j) hi4[j]=f2bf(v[j]);
  *(u16x4*)(cA + (size_t)b*5120 + c0) = hi4;
  if (c0 < 1024){
    u16x4 lo4;
    #pragma unroll
    for (int j=0;j<4;++j) lo4[j]=f2bf(v[j]-bf2f(hi4[j]));
    *(u16x4*)(xlo + (size_t)b*1024 + c0) = lo4;
  }
}

// surfaced via dot-product identity (no atan2). bf16 into cA[:,3072:5120]; f32 only for flagged rows.
__global__ __launch_bounds__(256) void prep_surf(const float* __restrict__ xc, const float* __restrict__ dp,
                                                 const int* __restrict__ smap, float* __restrict__ Scmp,
                                                 u16* __restrict__ cA, int cap){
  int i = blockIdx.x*256 + threadIdx.x;   // over 4096*1024
  int b = i >> 10, h = i & 1023;
  f32x2 z = *(const f32x2*)(xc + 2*(size_t)i);
  f32x2 d = *(const f32x2*)(dp + 2*(size_t)i);
  // T = cos^2((pa-pb)/2) = 0.5*(1+cos(pa-pb)); cos via normalized dot with ref's +1e-10 shifts
  float zx = z[0] + 1e-10f, dx = d[0] + 1e-10f;
  float hz = sqrtf(zx*zx + z[1]*z[1]);
  float hd = sqrtf(dx*dx + d[1]*d[1]);
  float cosd = (zx*dx + z[1]*d[1]) / fmaxf(hz*hd, 1e-30f);
  float T = 0.5f + 0.5f*cosd;
  float dmag = sqrtf(d[0]*d[0] + d[1]*d[1] + 1e-8f);
  float dscale = sqrtf(fminf(fmaxf(dmag, 1e-6f), 20.0f));
  float s = T * dscale / (dmag + 1e-8f);
  float o0 = d[0]*s, o1 = d[1]*s;
  u32 pk = (u32)f2bf(o0) | ((u32)f2bf(o1) << 16);
  *(u32*)&cA[(size_t)b*5120 + 3072 + 2*h] = pk;
  int p = smap[b];
  if (p >= 0 && p < cap)
    *(f32x2*)(Scmp + ((size_t)p*1024 + h)*2) = f32x2{o0, o1};
}

// rows with small temperature. out[0]=count(capped), out[1..]=rows; smap[b]=slot or -1
__global__ __launch_bounds__(256) void flag_rows(const float* __restrict__ bp, int* __restrict__ out,
                                                 int* __restrict__ smap, int cap){
  __shared__ int cnt;
  if (threadIdx.x==0) cnt=0;
  __syncthreads();
  for (int i=threadIdx.x; i<4096; i+=256){
    int p = -1;
    if (bp[i] < 0.04f){
      p = atomicAdd(&cnt,1);
      if (p < cap) out[1+p]=i;
    }
    smap[i] = p;
  }
  __syncthreads();
  if (threadIdx.x==0) out[0] = min(cnt, cap);
}

// write bias into rawfio rows that the split-K fixup will re-accumulate
__global__ __launch_bounds__(256) void fix_init(const int* __restrict__ smap, const int* __restrict__ cr,
    const float* __restrict__ b0, const float* __restrict__ b1, const float* __restrict__ b2,
    float* __restrict__ C){
  int b = blockIdx.x;
  int p = smap[b];
  if (p < 0 || p >= cr[0]) return;
  #pragma unroll
  for (int j0=0; j0<3072; j0+=256){
    int j = j0 + threadIdx.x;
    float bb = (j<1024) ? b0[j] : ((j<2048) ? b1[j-1024] : b2[j-2048]);
    C[(size_t)b*3072 + j] = bb;
  }
}

// ---------------- fast pure-bf16 GEMM (m97 structure + 4-way swizzle + XCD swizzle) ----------------
// C[m][n] = sum_k A[m][k]*B[n][k] + bias(n).  SPLIT: 3-pass hi/lo. NB: 1- or 3-segment bias.
template<bool SPLIT, bool OUTBF, int NB>
__global__ __launch_bounds__(256) void gemm_fast(
    const u16* __restrict__ Ah, int lda,
    const u16* __restrict__ Al, int ldal,
    const u16* __restrict__ Bh, int ldb,
    const u16* __restrict__ Bl,
    const float* __restrict__ bias0, const float* __restrict__ bias1, const float* __restrict__ bias2,
    float* __restrict__ Cf, u16* __restrict__ Cb, int ldc, int K)
{
  __shared__ u16 sAh[128*32];
  __shared__ u16 sBh[128*32];
  __shared__ u16 sAl[SPLIT?128*32:8];
  __shared__ u16 sBl[SPLIT?128*32:8];

  const int tid=threadIdx.x, lane=tid&63, w=tid>>6;

  // bijective XCD swizzle (grids are multiples of 8)
  const int gx = gridDim.x;
  const int nwg = gx * gridDim.y;
  const int lin = blockIdx.y*gx + blockIdx.x;
  const int sw = (lin & 7)*(nwg >> 3) + (lin >> 3);
  const int m0 = (sw / gx)*128, n0 = (sw % gx)*128;

  const int wm=(w>>1), wn=w&1, l16=lane&15, hi16=lane>>4;

  const int c0=(w*2+0)*64+lane, c1=c0+64;
  const int r0=c0>>2, sp0=(c0&3)^(r0&3);
  const int r1=c1>>2, sp1=(c1&3)^(r1&3);
  u16* lA0 = sAh + (w*2+0)*512; u16* lA1 = sAh + (w*2+1)*512;
  u16* lB0 = sBh + (w*2+0)*512; u16* lB1 = sBh + (w*2+1)*512;
  const u16* A0 = Ah + (size_t)(m0+r0)*lda + sp0*8;
  const u16* A1 = Ah + (size_t)(m0+r1)*lda + sp1*8;
  const u16* B0 = Bh + (size_t)(n0+r0)*ldb + sp0*8;
  const u16* B1 = Bh + (size_t)(n0+r1)*ldb + sp1*8;
  const u16 *A0l=nullptr,*A1l=nullptr,*B0l=nullptr,*B1l=nullptr;
  u16 *lA0l=nullptr,*lA1l=nullptr,*lB0l=nullptr,*lB1l=nullptr;
  if constexpr(SPLIT){
    A0l = Al + (size_t)(m0+r0)*ldal + sp0*8;
    A1l = Al + (size_t)(m0+r1)*ldal + sp1*8;
    B0l = Bl + (size_t)(n0+r0)*ldb  + sp0*8;
    B1l = Bl + (size_t)(n0+r1)*ldb  + sp1*8;
    lA0l = sAl + (w*2+0)*512; lA1l = sAl + (w*2+1)*512;
    lB0l = sBl + (w*2+0)*512; lB1l = sBl + (w*2+1)*512;
  }

  const int axor = (hi16 ^ (l16&3))*8;
  const int aoff = (wm*64 + l16)*32 + axor;
  const int boff = (wn*64 + l16)*32 + axor;

  f32x4 acc[4][4];
  #pragma unroll
  for (int a=0;a<4;++a)
    #pragma unroll
    for (int b=0;b<4;++b) acc[a][b] = f32x4{0.f,0.f,0.f,0.f};

  for (int k0=0; k0<K; k0+=32){
    gload_lds16(A0+k0, lA0);
    gload_lds16(A1+k0, lA1);
    gload_lds16(B0+k0, lB0);
    gload_lds16(B1+k0, lB1);
    if constexpr(SPLIT){
      gload_lds16(A0l+k0, lA0l);
      gload_lds16(A1l+k0, lA1l);
      gload_lds16(B0l+k0, lB0l);
      gload_lds16(B1l+k0, lB1l);
    }
    __syncthreads();
    bf16x8 fa[4], fb[4], fal[4], fbl[4];
    #pragma unroll
    for (int f=0; f<4; ++f){
      fa[f] = *(const bf16x8*)&sAh[aoff + f*512];
      fb[f] = *(const bf16x8*)&sBh[boff + f*512];
      if constexpr(SPLIT){
        fal[f] = *(const bf16x8*)&sAl[aoff + f*512];
        fbl[f] = *(const bf16x8*)&sBl[boff + f*512];
      }
    }
    #pragma unroll
    for (int fm=0; fm<4; ++fm){
      #pragma unroll
      for (int fn=0; fn<4; ++fn){
        acc[fm][fn] = __builtin_amdgcn_mfma_f32_16x16x32_bf16(fa[fm], fb[fn], acc[fm][fn], 0,0,0);
        if constexpr(SPLIT){
          acc[fm][fn] = __builtin_amdgcn_mfma_f32_16x16x32_bf16(fal[fm], fb[fn],  acc[fm][fn], 0,0,0);
          acc[fm][fn] = __builtin_amdgcn_mfma_f32_16x16x32_bf16(fa[fm],  fbl[fn], acc[fm][fn], 0,0,0);
        }
      }
    }
    __syncthreads();
  }

  #pragma unroll
  for (int fm=0; fm<4; ++fm){
    int grow = m0 + wm*64 + fm*16 + hi16*4;
    #pragma unroll
    for (int fn=0; fn<4; ++fn){
      int gcol = n0 + wn*64 + fn*16 + l16;
      float bb;
      if constexpr(NB==3) bb = (gcol<1024) ? bias0[gcol] : ((gcol<2048) ? bias1[gcol-1024] : bias2[gcol-2048]);
      else bb = bias0[gcol];
      #pragma unroll
      for (int r2=0;r2<4;++r2){
        float v = acc[fm][fn][r2] + bb;
        if constexpr(OUTBF) Cb[(size_t)(grow+r2)*ldc + gcol] = f2bf(v);
        else                Cf[(size_t)(grow+r2)*ldc + gcol] = v;
      }
    }
  }
}

// ---------------- fixup: precise 3-pass for flagged rows, SPLIT-K ----------------
#define LSTR 40
#define FIX_KC 8
#define FIX_KLEN 640
__global__ __launch_bounds__(256) void gemm_fix_sk(
    const float* __restrict__ Xs, const float* __restrict__ Hs,
    const float* __restrict__ Scmp, const int* __restrict__ smap,
    const float* __restrict__ W0, const float* __restrict__ W1, const float* __restrict__ W2,
    const int* __restrict__ cr, float* __restrict__ C)
{
  const int count = cr[0];
  const int m0 = blockIdx.y * 128;
  if (m0 >= count) return;
  const int* rows = cr + 1;
  const int kbeg = blockIdx.z * FIX_KLEN;
  const int kend = kbeg + FIX_KLEN;

  __shared__ u16 sAh[128*LSTR];
  __shared__ u16 sAl[128*LSTR];
  __shared__ u16 sBh[128*LSTR];
  __shared__ u16 sBl[128*LSTR];

  const int tid = threadIdx.x;
  const int n0 = blockIdx.x * 128;
  int seg = n0 >> 10;
  const float* W = (seg==0) ? W0 : (seg==1 ? W1 : W2);
  int nw = n0 & 1023;

  const int wave = tid >> 6, lane = tid & 63;
  const int wm = wave >> 1, wn = wave & 1;
  const int l16 = lane & 15, lk8 = (lane >> 4) * 8;

  f32x4 acc[4][4];
  #pragma unroll
  for (int a=0;a<4;++a)
    #pragma unroll
    for (int b=0;b<4;++b) acc[a][b] = f32x4{0.f,0.f,0.f,0.f};

  for (int k0 = kbeg; k0 < kend; k0 += 32){
    #pragma unroll
    for (int i=0;i<4;++i){
      int flat = tid + i*256;
      int r  = flat >> 3;
      int c4 = flat & 7;
      int kk = k0 + c4*4;
      int mrow = rows[min(m0 + r, count-1)];
      const float* srcA;
      if (kk < 1024)      srcA = Xs + (size_t)mrow*1024 + kk;
      else if (kk < 3072) srcA = Hs + (size_t)mrow*2048 + (kk - 1024);
      else                srcA = Scmp + (size_t)smap[mrow]*2048 + (kk - 3072);
      f32x4 va = *(const f32x4*)srcA;
      f32x4 vb = *(const f32x4*)(W + (size_t)(nw + r)*5120 + kk);
      u16x4 ah, bh, al, bl;
      #pragma unroll
      for (int j=0;j<4;++j){
        u16 hA = f2bf(va[j]); ah[j] = hA; al[j] = f2bf(va[j] - bf2f(hA));
        u16 hB = f2bf(vb[j]); bh[j] = hB; bl[j] = f2bf(vb[j] - bf2f(hB));
      }
      int o = r*LSTR + c4*4;
      *(u16x4*)&sAh[o] = ah;
      *(u16x4*)&sBh[o] = bh;
      *(u16x4*)&sAl[o] = al;
      *(u16x4*)&sBl[o] = bl;
    }
    __syncthreads();
    bf16x8 fah[4], fbh[4], fal[4], fbl[4];
    #pragma unroll
    for (int f=0; f<4; ++f){
      int ra  = (wm*64 + f*16 + l16)*LSTR + lk8;
      int rb2 = (wn*64 + f*16 + l16)*LSTR + lk8;
      fah[f] = *(const bf16x8*)&sAh[ra];
      fbh[f] = *(const bf16x8*)&sBh[rb2];
      fal[f] = *(const bf16x8*)&sAl[ra];
      fbl[f] = *(const bf16x8*)&sBl[rb2];
    }
    #pragma unroll
    for (int fm=0; fm<4; ++fm){
      #pragma unroll
      for (int fn=0; fn<4; ++fn){
        acc[fm][fn] = __builtin_amdgcn_mfma_f32_16x16x32_bf16(fah[fm], fbh[fn], acc[fm][fn], 0,0,0);
        acc[fm][fn] = __builtin_amdgcn_mfma_f32_16x16x32_bf16(fal[fm], fbh[fn], acc[fm][fn], 0,0,0);
        acc[fm][fn] = __builtin_amdgcn_mfma_f32_16x16x32_bf16(fah[fm], fbl[fn], acc[fm][fn], 0,0,0);
      }
    }
    __syncthreads();
  }

  #pragma unroll
  for (int fm=0; fm<4; ++fm){
    int trow = wm*64 + fm*16 + (lane>>4)*4;
    #pragma unroll
    for (int fn=0; fn<4; ++fn){
      int lcol = wn*64 + fn*16 + l16;
      #pragma unroll
      for (int r2=0;r2<4;++r2){
        int mi = m0 + trow + r2;
        if (mi < count){
          int mrow = rows[mi];
          atomicAdd(&C[(size_t)mrow*3072 + (n0 + lcol)], acc[fm][fn][r2]);
        }
      }
    }
  }
}

// ---------------- epilogue (transcendental-free gates) ----------------
__global__ __launch_bounds__(256) void epilogue(
    const float* __restrict__ rawfio, const u16* __restrict__ rawg,
    const float* __restrict__ c_prev, const float* __restrict__ d_prev,
    const float* __restrict__ b_prev, const float* __restrict__ theta,
    float* __restrict__ out)
{
  const int b = blockIdx.x;
  const int tid = threadIdx.x;
  float* Hout = out;
  float* Cout = out + (size_t)8388608;
  float* Dout = out + (size_t)16777216;
  float* Bout = out + (size_t)25165824;
  const float bp = b_prev[b];
  const float inv_t = 1.0f / (2.0f*bp + 1e-4f);
  float conv_acc = 0.f, emer_acc = 0.f;
  const size_t rb3 = (size_t)b*3072;
  const size_t rg = (size_t)b*2048;

  #pragma unroll
  for (int j=0;j<4;++j){
    int h = tid + j*256;
    float fr = rawfio[rb3 + h];
    float ir = rawfio[rb3 + 1024 + h];
    float og = rawfio[rb3 + 2048 + h];
    float g0 = bf2f(rawg[rg + h]);
    float g1 = bf2f(rawg[rg + 1024 + h]);

    float mx = fmaxf(fr, fmaxf(ir, og));
    float ef = __expf((fr-mx)*inv_t);
    float ei = __expf((ir-mx)*inv_t);
    float eo = __expf((og-mx)*inv_t);
    float inv_s = 1.0f/(ef+ei+eo);
    float ft = ef*inv_s, it = ei*inv_s, ot = eo*inv_s;

    f32x2 cp = *(const f32x2*)(c_prev + 2*((size_t)b*1024 + h));
    f32x2 dp = *(const f32x2*)(d_prev + 2*((size_t)b*1024 + h));

    // released + fractal compress via direction identity (no atan2/sincos)
    float r0 = (1.f-ft)*cp[0], r1 = (1.f-ft)*cp[1];
    float rm2 = r0*r0 + r1*r1;
    conv_acc += rm2 + 1e-8f;
    float rmag = sqrtf(rm2 + 1e-8f);            // _mag >= 1e-4, so max(.,1e-8) is moot
    float cm = __expf(0.66666667f * __logf(rmag));
    float rx = r0 + 1e-10f;
    float hr = fmaxf(sqrtf(rx*rx + r1*r1), 1e-30f);
    float invhr = cm / hr;
    float comp0 = fminf(fmaxf(rx*invhr, -10.f), 10.f);
    float comp1 = fminf(fmaxf(r1*invhr, -10.f), 10.f);

    float d0 = dp[0] + 0.01f*comp0;
    float d1 = dp[1] + 0.01f*comp1;
    float dmn = sqrtf(d0*d0 + d1*d1 + 1e-8f);
    if (dmn > 20.f){ float sc = 20.f/dmn; d0*=sc; d1*=sc; }

    float gt0 = ftanh(g0), gt1 = ftanh(g1);
    float cu0 = ft*cp[0] + it*gt0;
    float cu1 = ft*cp[1] + it*gt1;
    float th = theta[h];
    float sth, cth;
    __sincosf(th, &sth, &cth);
    float c0 = cth*cu0 - sth*cu1;
    float c1 = sth*cu0 + cth*cu1;
    float cs0 = ftanh(c0), cs1 = ftanh(c1);
    float hr0 = ot*cs0, hr1 = ot*cs1;

    // G = cos^2((ph(h)-ph(d))/2) = 0.5*(1 + dot/(|h||d|)) with ref's +1e-10 shifts
    float hx = hr0 + 1e-10f, dx = d0 + 1e-10f;
    float hh = sqrtf(hx*hx + hr1*hr1);
    float hd = sqrtf(dx*dx + d1*d1);
    float cosd = (hx*dx + hr1*d1) / fmaxf(hh*hd, 1e-30f);
    float G = 0.5f + 0.5f*cosd;
    float h0 = G*hr0, h1 = G*hr1;
    emer_acc += h0*h0 + h1*h1 + 1e-8f;

    h0 = (h0==h0)?h0:0.f;  h1 = (h1==h1)?h1:0.f;
    c0 = (c0==c0)?c0:0.f;  c1 = (c1==c1)?c1:0.f;
    d0 = (d0==d0)?d0:0.f;  d1 = (d1==d1)?d1:0.f;

    size_t oi = 2*((size_t)b*1024 + h);
    *(f32x2*)(Hout+oi) = f32x2{h0,h1};
    *(f32x2*)(Cout+oi) = f32x2{c0,c1};
    *(f32x2*)(Dout+oi) = f32x2{d0,d1};
  }

  #pragma unroll
  for (int off=32; off; off>>=1){
    conv_acc += __shfl_down(conv_acc, off);
    emer_acc += __shfl_down(emer_acc, off);
  }
  __shared__ float sred[8];
  int wv = tid>>6, ln = tid&63;
  if (ln==0){ sred[wv]=conv_acc; sred[4+wv]=emer_acc; }
  __syncthreads();
  if (tid==0){
    float cv = sred[0]+sred[1]+sred[2]+sred[3];
    float em = sred[4]+sred[5]+sred[6]+sred[7];
    float bm = cv/(cv+em+1e-8f);
    float bt = 0.99f*bp + 0.01f*bm;
    bt = (bt==bt)?bt:0.5f;
    Bout[b] = bt;
  }
}

extern "C" void kernel_launch(void* const* d_in, const int* in_sizes, int n_in,
                              void* d_out, int out_size, void* d_ws, size_t ws_size,
                              hipStream_t stream)
{
  const float* x_t    = (const float*)d_in[0];
  const float* h_prev = (const float*)d_in[1];
  const float* c_prev = (const float*)d_in[2];
  const float* d_prev = (const float*)d_in[3];
  const float* b_prev = (const float*)d_in[4];
  const float* Wf_w   = (const float*)d_in[5];
  const float* Wf_b   = (const float*)d_in[6];
  const float* Wi_w   = (const float*)d_in[7];
  const float* Wi_b   = (const float*)d_in[8];
  const float* Wo_w   = (const float*)d_in[9];
  const float* Wo_b   = (const float*)d_in[10];
  const float* Wc_w   = (const float*)d_in[11];
  const float* Wc_b   = (const float*)d_in[12];
  const float* Wr_w   = (const float*)d_in[13];
  const float* Wr_b   = (const float*)d_in[14];
  const float* theta  = (const float*)d_in[15];

  char* W = (char*)d_ws;
  // OFF0: rawfio f32 [4096][3072] = 50331648; xc f32 [4096][2048] aliased (dead before fio GEMM)
  float* rawfio = (float*)W;
  float* xc     = (float*)W;
  // OFF1 = 50331648: transient 16 MB: Wr_hi(4M)|Wr_lo(4M)|x_lo(8M), later raw_g bf16 [4096][2048]
  u16*   Wr_hi  = (u16*)(W + 50331648);
  u16*   Wr_lo  = (u16*)(W + 50331648 + 4194304);
  u16*   x_lo   = (u16*)(W + 50331648 + 8388608);
  u16*   raw_g  = (u16*)(W + 50331648);
  // OFF2 = 67108864: cA bf16 [4096][5120] = 41943040
  u16*   cA     = (u16*)(W + 67108864);
  // OFF3 = 109051904: WD3 bf16 [3072][5120] = 31457280 (fio), then Wc bf16 [2048][5120] reuse
  u16*   WD     = (u16*)(W + 109051904);
  // OFF4 = 140509184: idx (4097 ints) then smap (4096 ints)
  int*   idx    = (int*)(W + 140509184);
  int*   smap   = (int*)(W + 140509184 + 16388);
  // OFF5 = 140546048: surf_cmp f32 [cap][2048]
  float* Scmp   = (float*)(W + 140546048);
  long long avail = (long long)ws_size - 140546048LL;
  int cap = (int)(avail > 0 ? avail / 8192 : 0);
  if (cap > 1024) cap = 1024;

  dim3 blk(256);

  // 1. x,h -> cA[:,0:3072] + x_lo
  cvt_xh<<<dim3(3,4096), blk, 0, stream>>>(x_t, h_prev, cA, x_lo);
  // 2. Wr -> hi/lo
  cvt_hilo<<<2048, blk, 0, stream>>>(Wr_w, Wr_hi, Wr_lo, 524288);
  // 3. GEMM1 (split 3-pass): xc = x @ Wr^T + b
  gemm_fast<true,false,1><<<dim3(16,32), blk, 0, stream>>>(
      cA, 5120, x_lo, 1024, Wr_hi, 1024, Wr_lo,
      Wr_b, nullptr, nullptr, xc, nullptr, 2048, 1024);
  // 4. flag low-temperature rows
  flag_rows<<<1, blk, 0, stream>>>(b_prev, idx, smap, cap);
  // 5. surfaced -> cA[:,3072:5120] (+ compact f32 for flagged rows)
  prep_surf<<<16384, blk, 0, stream>>>(xc, d_prev, smap, Scmp, cA, cap);
  // 6. Wf,Wi,Wo -> WD3
  cvt_hi<<<5120, blk, 0, stream>>>(Wf_w, WD, 1310720);
  cvt_hi<<<5120, blk, 0, stream>>>(Wi_w, WD + (size_t)1024*5120, 1310720);
  cvt_hi<<<5120, blk, 0, stream>>>(Wo_w, WD + (size_t)2048*5120, 1310720);
  // 7. f/i/o merged (1-pass), 768 blocks
  gemm_fast<false,false,3><<<dim3(24,32), blk, 0, stream>>>(
      cA, 5120, nullptr, 0, WD, 5120, nullptr,
      Wf_b, Wi_b, Wo_b, rawfio, nullptr, 3072, 5120);
  // 8. bias-init flagged rows, then split-K precise fixup
  fix_init<<<4096, blk, 0, stream>>>(smap, idx, Wf_b, Wi_b, Wo_b, rawfio);
  gemm_fix_sk<<<dim3(24,8,FIX_KC), blk, 0, stream>>>(
      x_t, h_prev, Scmp, smap, Wf_w, Wi_w, Wo_w, idx, rawfio);
  // 9. Wc -> WD (reuse), g raw (1-pass, bf16 out into R1)
  cvt_hi<<<10240, blk, 0, stream>>>(Wc_w, WD, 2621440);
  gemm_fast<false,true,1><<<dim3(16,32), blk, 0, stream>>>(
      cA, 5120, nullptr, 0, WD, 5120, nullptr,
      Wc_b, nullptr, nullptr, nullptr, raw_g, 2048, 5120);
  // 10. epilogue
  epilogue<<<4096, blk, 0, stream>>>(rawfio, raw_g, c_prev, d_prev, b_prev, theta, (float*)d_out);
}

// Round 5
// 527.189 us; speedup vs baseline: 2.9549x; 1.0841x over previous
//
#include <hip/hip_runtime.h>
#include <math.h>

typedef unsigned short u16;
typedef unsigned int u32;
typedef u16 u16x4 __attribute__((ext_vector_type(4)));
typedef float f32x2 __attribute__((ext_vector_type(2)));
typedef float f32x4 __attribute__((ext_vector_type(4)));
typedef __bf16 bf16x8 __attribute__((ext_vector_type(8)));

__device__ __forceinline__ u16 f2bf(float f){
  u32 u = __builtin_bit_cast(u32, f);
  u32 r = u + 0x7FFFu + ((u >> 16) & 1u);
  return (u16)(r >> 16);
}
__device__ __forceinline__ float bf2f(u16 h){
  u32 u = ((u32)h) << 16;
  return __builtin_bit_cast(float, u);
}
__device__ __forceinline__ float ftanh(float x){
  float e = __expf(2.f*x);
  return 1.f - 2.f/(e+1.f);
}

typedef __attribute__((address_space(1))) const unsigned int gas_u32;
typedef __attribute__((address_space(3))) unsigned int las_u32;
__device__ __forceinline__ void gload_lds16(const void* g, void* l){
  __builtin_amdgcn_global_load_lds((gas_u32*)g, (las_u32*)l, 16, 0, 0);
}

// ---------------- converts ----------------
__global__ __launch_bounds__(256) void cvt_hi(const float* __restrict__ in, u16* __restrict__ out, int n4){
  int i = blockIdx.x*256 + threadIdx.x;
  if (i >= n4) return;
  f32x4 v = *(const f32x4*)(in + (size_t)i*4);
  u16x4 o;
  #pragma unroll
  for (int j=0;j<4;++j) o[j]=f2bf(v[j]);
  *(u16x4*)(out + (size_t)i*4) = o;
}

__global__ __launch_bounds__(256) void cvt_hilo(const float* __restrict__ in, u16* __restrict__ hi, u16* __restrict__ lo, int n4){
  int i = blockIdx.x*256 + threadIdx.x;
  if (i >= n4) return;
  f32x4 v = *(const f32x4*)(in + (size_t)i*4);
  u16x4 oh, ol;
  #pragma unroll
  for (int j=0;j<4;++j){ u16 h=f2bf(v[j]); oh[j]=h; ol[j]=f2bf(v[j]-bf2f(h)); }
  *(u16x4*)(hi + (size_t)i*4) = oh;
  *(u16x4*)(lo + (size_t)i*4) = ol;
}

// x,h -> cA_hi[:,0:3072] (bf16), x also -> x_lo
__global__ __launch_bounds__(256) void cvt_xh(const float* __restrict__ x, const float* __restrict__ h,
                                              u16* __restrict__ cA, u16* __restrict__ xlo){
  int b = blockIdx.y;
  int c0 = (blockIdx.x*256 + threadIdx.x)*4;
  f32x4 v;
  if (c0 < 1024) v = *(const f32x4*)(x + (size_t)b*1024 + c0);
  else           v = *(const f32x4*)(h + (size_t)b*2048 + (c0-1024));
  u16x4 hi4;
  #pragma unroll
  for (int j=0;j<4;++j) hi4[j]=f2bf(v[j]);
  *(u16x4*)(cA + (size_t)b*5120 + c0) = hi4;
  if (c0 < 1024){
    u16x4 lo4;
    #pragma unroll
    for (int j=0;j<4;++j) lo4[j]=f2bf(v[j]-bf2f(hi4[j]));
    *(u16x4*)(xlo + (size_t)b*1024 + c0) = lo4;
  }
}

// surfaced via dot-product identity (no atan2). bf16 into cA[:,3072:5120]; f32 only for flagged rows.
__global__ __launch_bounds__(256) void prep_surf(const float* __restrict__ xc, const float* __restrict__ dp,
                                                 const int* __restrict__ smap, float* __restrict__ Scmp,
                                                 u16* __restrict__ cA, int cap){
  int i = blockIdx.x*256 + threadIdx.x;   // over 4096*1024
  int b = i >> 10, h = i & 1023;
  f32x2 z = *(const f32x2*)(xc + 2*(size_t)i);
  f32x2 d = *(const f32x2*)(dp + 2*(size_t)i);
  float zx = z[0] + 1e-10f, dx = d[0] + 1e-10f;
  float hz = sqrtf(zx*zx + z[1]*z[1]);
  float hd = sqrtf(dx*dx + d[1]*d[1]);
  float cosd = (zx*dx + z[1]*d[1]) / fmaxf(hz*hd, 1e-30f);
  float T = 0.5f + 0.5f*cosd;
  float dmag = sqrtf(d[0]*d[0] + d[1]*d[1] + 1e-8f);
  float dscale = sqrtf(fminf(fmaxf(dmag, 1e-6f), 20.0f));
  float s = T * dscale / (dmag + 1e-8f);
  float o0 = d[0]*s, o1 = d[1]*s;
  u32 pk = (u32)f2bf(o0) | ((u32)f2bf(o1) << 16);
  *(u32*)&cA[(size_t)b*5120 + 3072 + 2*h] = pk;
  int p = smap[b];
  if (p >= 0 && p < cap)
    *(f32x2*)(Scmp + ((size_t)p*1024 + h)*2) = f32x2{o0, o1};
}

// rows with small temperature. out[0]=count(capped), out[1..]=rows; smap[b]=slot or -1
__global__ __launch_bounds__(256) void flag_rows(const float* __restrict__ bp, int* __restrict__ out,
                                                 int* __restrict__ smap, int cap){
  __shared__ int cnt;
  if (threadIdx.x==0) cnt=0;
  __syncthreads();
  for (int i=threadIdx.x; i<4096; i+=256){
    int p = -1;
    if (bp[i] < 0.04f){
      p = atomicAdd(&cnt,1);
      if (p < cap) out[1+p]=i;
    }
    smap[i] = p;
  }
  __syncthreads();
  if (threadIdx.x==0) out[0] = min(cnt, cap);
}

// write bias into rawfio rows that the split-K fixup will re-accumulate
__global__ __launch_bounds__(256) void fix_init(const int* __restrict__ smap, const int* __restrict__ cr,
    const float* __restrict__ b0, const float* __restrict__ b1, const float* __restrict__ b2,
    float* __restrict__ C){
  int b = blockIdx.x;
  int p = smap[b];
  if (p < 0 || p >= cr[0]) return;
  #pragma unroll
  for (int j0=0; j0<3072; j0+=256){
    int j = j0 + threadIdx.x;
    float bb = (j<1024) ? b0[j] : ((j<2048) ? b1[j-1024] : b2[j-2048]);
    C[(size_t)b*3072 + j] = bb;
  }
}

// ============ 8-phase 256-wide GEMM (T2+T3+T4+T5), K-split half-tiles ============
// C[m][n] = sum_k A[m][k]*B[n][k] + bias(n). NR=4 -> BN=256 (vmcnt 4); NR=2 -> BN=128 (vmcnt 3).
// LDS half-tile: 256(BM) x 32 cols bf16; swizzle slot ^= (row>>1)&3 (both stage-source and read).
#define LDA8(BUF,H,MH,J) (*(const bf16x8*)(sAc + ((BUF)*2+(H))*16384 + abase + (MH)*4096 + (J)*1024))
#define LDB8(BUF,H,N)    (*(const bf16x8*)(sBc + ((BUF)*2+(H))*BHTB + bbase + (N)*1024))
#define STG_A8(BUF,H,TT) { const u16* s_ = Ah + aS + (size_t)(TT)*64 + (H)*32; \
    gload_lds16(s_, dA + ((BUF)*2+(H))*8192); \
    gload_lds16(s_ + aS2, dA + ((BUF)*2+(H))*8192 + 4096); }
#define STG_B8(BUF,H,TT) { const u16* s_ = Bh + bS + (size_t)(TT)*64 + (H)*32; \
    gload_lds16(s_, dB + ((BUF)*2+(H))*(BHTB/2)); \
    if constexpr (NR==4){ gload_lds16(s_ + bS2, dB + ((BUF)*2+(H))*(BHTB/2) + 4096); } }
#define PH8(BUF,H,MH,RB,STG,DOW) do{ \
    bf16x8 af0 = LDA8(BUF,H,MH,0), af1 = LDA8(BUF,H,MH,1), af2 = LDA8(BUF,H,MH,2), af3 = LDA8(BUF,H,MH,3); \
    if (RB){ _Pragma("unroll") for(int n_=0;n_<NR;++n_) bfr[n_] = LDB8(BUF,H,n_); } \
    STG; \
    asm volatile("" ::: "memory"); \
    __builtin_amdgcn_s_barrier(); \
    asm volatile("s_waitcnt lgkmcnt(0)" ::: "memory"); \
    __builtin_amdgcn_sched_barrier(0); \
    __builtin_amdgcn_s_setprio(1); \
    _Pragma("unroll") for(int n_=0;n_<NR;++n_){ \
      acc[(MH)*4+0][n_] = __builtin_amdgcn_mfma_f32_16x16x32_bf16(af0, bfr[n_], acc[(MH)*4+0][n_],0,0,0); \
      acc[(MH)*4+1][n_] = __builtin_amdgcn_mfma_f32_16x16x32_bf16(af1, bfr[n_], acc[(MH)*4+1][n_],0,0,0); \
      acc[(MH)*4+2][n_] = __builtin_amdgcn_mfma_f32_16x16x32_bf16(af2, bfr[n_], acc[(MH)*4+2][n_],0,0,0); \
      acc[(MH)*4+3][n_] = __builtin_amdgcn_mfma_f32_16x16x32_bf16(af3, bfr[n_], acc[(MH)*4+3][n_],0,0,0); } \
    __builtin_amdgcn_s_setprio(0); \
    if (DOW) { asm volatile("s_waitcnt vmcnt(%0)" :: "i"(VN) : "memory"); } \
    asm volatile("" ::: "memory"); \
    __builtin_amdgcn_s_barrier(); \
    __builtin_amdgcn_sched_barrier(0); \
  }while(0)

template<int NR, bool OUTBF, int NB>
__global__ __launch_bounds__(512) void gemm8p(
    const u16* __restrict__ Ah, int lda,
    const u16* __restrict__ Bh, int ldb,
    const float* __restrict__ bias0, const float* __restrict__ bias1, const float* __restrict__ bias2,
    float* __restrict__ Cf, u16* __restrict__ Cb, int ldc, int K)
{
  constexpr int BN   = NR*64;
  constexpr int BHTB = BN*64;          // bytes per B half-tile (BN rows x 32 cols x 2B)
  constexpr int VN   = (NR==4) ? 4 : 3;
  __shared__ u16 sA[4*8192];           // [buf][h][256][32]
  __shared__ u16 sB[4*(NR*2048)];      // [buf][h][BN][32]
  const char* sAc = (const char*)sA;
  const char* sBc = (const char*)sB;

  const int tid = threadIdx.x, lane = tid&63, w8 = tid>>6;
  const int wr = w8>>2, wc = w8&3;
  const int l16 = lane&15;

  // bijective XCD swizzle (grid sizes are multiples of 8)
  const int gx = gridDim.x, nwg = gx*gridDim.y;
  const int lin = blockIdx.y*gx + blockIdx.x;
  const int sw = (lin&7)*(nwg>>3) + (lin>>3);
  const int m0 = (sw / gx)*256, n0 = (sw % gx)*BN;

  // staging: thread stages chunk c=tid (row=tid>>2, lds slot=tid&3) [+ chunk tid+512 for 256-row tiles]
  const int rowS  = tid>>2;
  const int ksS   = (tid&3) ^ ((tid>>3)&3);            // pre-swizzled global k-slot (involution)
  const size_t aS = (size_t)(m0 + rowS)*lda + ksS*8;
  const size_t aS2= (size_t)128*lda;
  const size_t bS = (size_t)(n0 + rowS)*ldb + ksS*8;
  const size_t bS2= (size_t)128*ldb;
  u16* dA = sA + w8*512;                                // wave-uniform LDS bases
  u16* dB = sB + w8*512;

  // ds_read: lane reads row base+l16, k-slot lane>>4, swizzled slot = (lane>>4) ^ ((l16>>1)&3)
  const int aslot = (lane>>4) ^ ((l16>>1)&3);
  const int abase = (wr*128 + l16)*64 + aslot*16;       // bytes within A half-tile
  const int bbase = (wc*(NR*16) + l16)*64 + aslot*16;   // bytes within B half-tile

  f32x4 acc[8][NR];
  #pragma unroll
  for (int a=0;a<8;++a)
    #pragma unroll
    for (int b=0;b<NR;++b) acc[a][b] = f32x4{0.f,0.f,0.f,0.f};
  bf16x8 bfr[NR];

  const int NT = K>>6, NITER = K>>7;

  // prologue: stage T0{A0,B0,A1,B1}, T1{A0,B0}; wait until T0 landed (T1.A0/B0 stay in flight)
  STG_A8(0,0,0) STG_B8(0,0,0) STG_A8(0,1,0) STG_B8(0,1,0) STG_A8(1,0,1) STG_B8(1,0,1)
  asm volatile("s_waitcnt vmcnt(%0)" :: "i"(VN) : "memory");
  asm volatile("" ::: "memory");
  __builtin_amdgcn_s_barrier();
  __builtin_amdgcn_sched_barrier(0);

  for (int i=0; i<NITER; ++i){
    const int t1 = 2*i+1;
    const int ta = min(2*i+2, NT-1);   // clamped: keeps vmcnt ledger exact at the tail
    const int tb = min(2*i+3, NT-1);
    PH8(0,0,0,true,  STG_A8(1,1,t1), false);  // ph0: T0 ks0 mh0 | stage T1.A1
    PH8(0,0,1,false, STG_B8(1,1,t1), false);  // ph1: T0 ks0 mh1 | stage T1.B1
    PH8(0,1,0,true,  STG_A8(0,0,ta), false);  // ph2: T0 ks1 mh0 | stage (T0+2).A0
    PH8(0,1,1,false, STG_B8(0,0,ta), true);   // ph3: T0 ks1 mh1 | stage (T0+2).B0 | vmcnt
    PH8(1,0,0,true,  STG_A8(0,1,ta), false);  // ph4: T1 ks0 mh0 | stage (T0+2).A1
    PH8(1,0,1,false, STG_B8(0,1,ta), false);  // ph5: T1 ks0 mh1 | stage (T0+2).B1
    PH8(1,1,0,true,  STG_A8(1,0,tb), false);  // ph6: T1 ks1 mh0 | stage (T1+2).A0
    PH8(1,1,1,false, STG_B8(1,0,tb), true);   // ph7: T1 ks1 mh1 | stage (T1+2).B0 | vmcnt
  }
  asm volatile("s_waitcnt vmcnt(0)" ::: "memory");  // drain before endpgm

  #pragma unroll
  for (int mf=0; mf<8; ++mf){
    int grow = m0 + wr*128 + mf*16 + (lane>>4)*4;
    #pragma unroll
    for (int n=0; n<NR; ++n){
      int gcol = n0 + wc*(NR*16) + n*16 + l16;
      float bb;
      if constexpr(NB==3) bb = (gcol<1024) ? bias0[gcol] : ((gcol<2048) ? bias1[gcol-1024] : bias2[gcol-2048]);
      else bb = bias0[gcol];
      #pragma unroll
      for (int r2=0;r2<4;++r2){
        float v = acc[mf][n][r2] + bb;
        if constexpr(OUTBF) Cb[(size_t)(grow+r2)*ldc + gcol] = f2bf(v);
        else                Cf[(size_t)(grow+r2)*ldc + gcol] = v;
      }
    }
  }
}

// ---------------- fast 128^2 GEMM (m97 structure) — used for split-precision GEMM1 ----------------
template<bool SPLIT, bool OUTBF, int NB>
__global__ __launch_bounds__(256) void gemm_fast(
    const u16* __restrict__ Ah, int lda,
    const u16* __restrict__ Al, int ldal,
    const u16* __restrict__ Bh, int ldb,
    const u16* __restrict__ Bl,
    const float* __restrict__ bias0, const float* __restrict__ bias1, const float* __restrict__ bias2,
    float* __restrict__ Cf, u16* __restrict__ Cb, int ldc, int K)
{
  __shared__ u16 sAh[128*32];
  __shared__ u16 sBh[128*32];
  __shared__ u16 sAl[SPLIT?128*32:8];
  __shared__ u16 sBl[SPLIT?128*32:8];

  const int tid=threadIdx.x, lane=tid&63, w=tid>>6;

  const int gx = gridDim.x;
  const int nwg = gx * gridDim.y;
  const int lin = blockIdx.y*gx + blockIdx.x;
  const int sw = (lin & 7)*(nwg >> 3) + (lin >> 3);
  const int m0 = (sw / gx)*128, n0 = (sw % gx)*128;

  const int wm=(w>>1), wn=w&1, l16=lane&15, hi16=lane>>4;

  const int c0=(w*2+0)*64+lane, c1=c0+64;
  const int r0=c0>>2, sp0=(c0&3)^(r0&3);
  const int r1=c1>>2, sp1=(c1&3)^(r1&3);
  u16* lA0 = sAh + (w*2+0)*512; u16* lA1 = sAh + (w*2+1)*512;
  u16* lB0 = sBh + (w*2+0)*512; u16* lB1 = sBh + (w*2+1)*512;
  const u16* A0 = Ah + (size_t)(m0+r0)*lda + sp0*8;
  const u16* A1 = Ah + (size_t)(m0+r1)*lda + sp1*8;
  const u16* B0 = Bh + (size_t)(n0+r0)*ldb + sp0*8;
  const u16* B1 = Bh + (size_t)(n0+r1)*ldb + sp1*8;
  const u16 *A0l=nullptr,*A1l=nullptr,*B0l=nullptr,*B1l=nullptr;
  u16 *lA0l=nullptr,*lA1l=nullptr,*lB0l=nullptr,*lB1l=nullptr;
  if constexpr(SPLIT){
    A0l = Al + (size_t)(m0+r0)*ldal + sp0*8;
    A1l = Al + (size_t)(m0+r1)*ldal + sp1*8;
    B0l = Bl + (size_t)(n0+r0)*ldb  + sp0*8;
    B1l = Bl + (size_t)(n0+r1)*ldb  + sp1*8;
    lA0l = sAl + (w*2+0)*512; lA1l = sAl + (w*2+1)*512;
    lB0l = sBl + (w*2+0)*512; lB1l = sBl + (w*2+1)*512;
  }

  const int axor = (hi16 ^ (l16&3))*8;
  const int aoff = (wm*64 + l16)*32 + axor;
  const int boff = (wn*64 + l16)*32 + axor;

  f32x4 acc[4][4];
  #pragma unroll
  for (int a=0;a<4;++a)
    #pragma unroll
    for (int b=0;b<4;++b) acc[a][b] = f32x4{0.f,0.f,0.f,0.f};

  for (int k0=0; k0<K; k0+=32){
    gload_lds16(A0+k0, lA0);
    gload_lds16(A1+k0, lA1);
    gload_lds16(B0+k0, lB0);
    gload_lds16(B1+k0, lB1);
    if constexpr(SPLIT){
      gload_lds16(A0l+k0, lA0l);
      gload_lds16(A1l+k0, lA1l);
      gload_lds16(B0l+k0, lB0l);
      gload_lds16(B1l+k0, lB1l);
    }
    __syncthreads();
    bf16x8 fa[4], fb[4], fal[4], fbl[4];
    #pragma unroll
    for (int f=0; f<4; ++f){
      fa[f] = *(const bf16x8*)&sAh[aoff + f*512];
      fb[f] = *(const bf16x8*)&sBh[boff + f*512];
      if constexpr(SPLIT){
        fal[f] = *(const bf16x8*)&sAl[aoff + f*512];
        fbl[f] = *(const bf16x8*)&sBl[boff + f*512];
      }
    }
    #pragma unroll
    for (int fm=0; fm<4; ++fm){
      #pragma unroll
      for (int fn=0; fn<4; ++fn){
        acc[fm][fn] = __builtin_amdgcn_mfma_f32_16x16x32_bf16(fa[fm], fb[fn], acc[fm][fn], 0,0,0);
        if constexpr(SPLIT){
          acc[fm][fn] = __builtin_amdgcn_mfma_f32_16x16x32_bf16(fal[fm], fb[fn],  acc[fm][fn], 0,0,0);
          acc[fm][fn] = __builtin_amdgcn_mfma_f32_16x16x32_bf16(fa[fm],  fbl[fn], acc[fm][fn], 0,0,0);
        }
      }
    }
    __syncthreads();
  }

  #pragma unroll
  for (int fm=0; fm<4; ++fm){
    int grow = m0 + wm*64 + fm*16 + hi16*4;
    #pragma unroll
    for (int fn=0; fn<4; ++fn){
      int gcol = n0 + wn*64 + fn*16 + l16;
      float bb;
      if constexpr(NB==3) bb = (gcol<1024) ? bias0[gcol] : ((gcol<2048) ? bias1[gcol-1024] : bias2[gcol-2048]);
      else bb = bias0[gcol];
      #pragma unroll
      for (int r2=0;r2<4;++r2){
        float v = acc[fm][fn][r2] + bb;
        if constexpr(OUTBF) Cb[(size_t)(grow+r2)*ldc + gcol] = f2bf(v);
        else                Cf[(size_t)(grow+r2)*ldc + gcol] = v;
      }
    }
  }
}

// ---------------- fixup: precise 3-pass for flagged rows, SPLIT-K ----------------
#define LSTR 40
#define FIX_KC 8
#define FIX_KLEN 640
__global__ __launch_bounds__(256) void gemm_fix_sk(
    const float* __restrict__ Xs, const float* __restrict__ Hs,
    const float* __restrict__ Scmp, const int* __restrict__ smap,
    const float* __restrict__ W0, const float* __restrict__ W1, const float* __restrict__ W2,
    const int* __restrict__ cr, float* __restrict__ C)
{
  const int count = cr[0];
  const int m0 = blockIdx.y * 128;
  if (m0 >= count) return;
  const int* rows = cr + 1;
  const int kbeg = blockIdx.z * FIX_KLEN;
  const int kend = kbeg + FIX_KLEN;

  __shared__ u16 sAh[128*LSTR];
  __shared__ u16 sAl[128*LSTR];
  __shared__ u16 sBh[128*LSTR];
  __shared__ u16 sBl[128*LSTR];

  const int tid = threadIdx.x;
  const int n0 = blockIdx.x * 128;
  int seg = n0 >> 10;
  const float* W = (seg==0) ? W0 : (seg==1 ? W1 : W2);
  int nw = n0 & 1023;

  const int wave = tid >> 6, lane = tid & 63;
  const int wm = wave >> 1, wn = wave & 1;
  const int l16 = lane & 15, lk8 = (lane >> 4) * 8;

  f32x4 acc[4][4];
  #pragma unroll
  for (int a=0;a<4;++a)
    #pragma unroll
    for (int b=0;b<4;++b) acc[a][b] = f32x4{0.f,0.f,0.f,0.f};

  for (int k0 = kbeg; k0 < kend; k0 += 32){
    #pragma unroll
    for (int i=0;i<4;++i){
      int flat = tid + i*256;
      int r  = flat >> 3;
      int c4 = flat & 7;
      int kk = k0 + c4*4;
      int mrow = rows[min(m0 + r, count-1)];
      const float* srcA;
      if (kk < 1024)      srcA = Xs + (size_t)mrow*1024 + kk;
      else if (kk < 3072) srcA = Hs + (size_t)mrow*2048 + (kk - 1024);
      else                srcA = Scmp + (size_t)smap[mrow]*2048 + (kk - 3072);
      f32x4 va = *(const f32x4*)srcA;
      f32x4 vb = *(const f32x4*)(W + (size_t)(nw + r)*5120 + kk);
      u16x4 ah, bh, al, bl;
      #pragma unroll
      for (int j=0;j<4;++j){
        u16 hA = f2bf(va[j]); ah[j] = hA; al[j] = f2bf(va[j] - bf2f(hA));
        u16 hB = f2bf(vb[j]); bh[j] = hB; bl[j] = f2bf(vb[j] - bf2f(hB));
      }
      int o = r*LSTR + c4*4;
      *(u16x4*)&sAh[o] = ah;
      *(u16x4*)&sBh[o] = bh;
      *(u16x4*)&sAl[o] = al;
      *(u16x4*)&sBl[o] = bl;
    }
    __syncthreads();
    bf16x8 fah[4], fbh[4], fal[4], fbl[4];
    #pragma unroll
    for (int f=0; f<4; ++f){
      int ra  = (wm*64 + f*16 + l16)*LSTR + lk8;
      int rb2 = (wn*64 + f*16 + l16)*LSTR + lk8;
      fah[f] = *(const bf16x8*)&sAh[ra];
      fbh[f] = *(const bf16x8*)&sBh[rb2];
      fal[f] = *(const bf16x8*)&sAl[ra];
      fbl[f] = *(const bf16x8*)&sBl[rb2];
    }
    #pragma unroll
    for (int fm=0; fm<4; ++fm){
      #pragma unroll
      for (int fn=0; fn<4; ++fn){
        acc[fm][fn] = __builtin_amdgcn_mfma_f32_16x16x32_bf16(fah[fm], fbh[fn], acc[fm][fn], 0,0,0);
        acc[fm][fn] = __builtin_amdgcn_mfma_f32_16x16x32_bf16(fal[fm], fbh[fn], acc[fm][fn], 0,0,0);
        acc[fm][fn] = __builtin_amdgcn_mfma_f32_16x16x32_bf16(fah[fm], fbl[fn], acc[fm][fn], 0,0,0);
      }
    }
    __syncthreads();
  }

  #pragma unroll
  for (int fm=0; fm<4; ++fm){
    int trow = wm*64 + fm*16 + (lane>>4)*4;
    #pragma unroll
    for (int fn=0; fn<4; ++fn){
      int lcol = wn*64 + fn*16 + l16;
      #pragma unroll
      for (int r2=0;r2<4;++r2){
        int mi = m0 + trow + r2;
        if (mi < count){
          int mrow = rows[mi];
          atomicAdd(&C[(size_t)mrow*3072 + (n0 + lcol)], acc[fm][fn][r2]);
        }
      }
    }
  }
}

// ---------------- epilogue (transcendental-free gates) ----------------
__global__ __launch_bounds__(256) void epilogue(
    const float* __restrict__ rawfio, const u16* __restrict__ rawg,
    const float* __restrict__ c_prev, const float* __restrict__ d_prev,
    const float* __restrict__ b_prev, const float* __restrict__ theta,
    float* __restrict__ out)
{
  const int b = blockIdx.x;
  const int tid = threadIdx.x;
  float* Hout = out;
  float* Cout = out + (size_t)8388608;
  float* Dout = out + (size_t)16777216;
  float* Bout = out + (size_t)25165824;
  const float bp = b_prev[b];
  const float inv_t = 1.0f / (2.0f*bp + 1e-4f);
  float conv_acc = 0.f, emer_acc = 0.f;
  const size_t rb3 = (size_t)b*3072;
  const size_t rg = (size_t)b*2048;

  #pragma unroll
  for (int j=0;j<4;++j){
    int h = tid + j*256;
    float fr = rawfio[rb3 + h];
    float ir = rawfio[rb3 + 1024 + h];
    float og = rawfio[rb3 + 2048 + h];
    float g0 = bf2f(rawg[rg + h]);
    float g1 = bf2f(rawg[rg + 1024 + h]);

    float mx = fmaxf(fr, fmaxf(ir, og));
    float ef = __expf((fr-mx)*inv_t);
    float ei = __expf((ir-mx)*inv_t);
    float eo = __expf((og-mx)*inv_t);
    float inv_s = 1.0f/(ef+ei+eo);
    float ft = ef*inv_s, it = ei*inv_s, ot = eo*inv_s;

    f32x2 cp = *(const f32x2*)(c_prev + 2*((size_t)b*1024 + h));
    f32x2 dp = *(const f32x2*)(d_prev + 2*((size_t)b*1024 + h));

    float r0 = (1.f-ft)*cp[0], r1 = (1.f-ft)*cp[1];
    float rm2 = r0*r0 + r1*r1;
    conv_acc += rm2 + 1e-8f;
    float rmag = sqrtf(rm2 + 1e-8f);
    float cm = __expf(0.66666667f * __logf(rmag));
    float rx = r0 + 1e-10f;
    float hr = fmaxf(sqrtf(rx*rx + r1*r1), 1e-30f);
    float invhr = cm / hr;
    float comp0 = fminf(fmaxf(rx*invhr, -10.f), 10.f);
    float comp1 = fminf(fmaxf(r1*invhr, -10.f), 10.f);

    float d0 = dp[0] + 0.01f*comp0;
    float d1 = dp[1] + 0.01f*comp1;
    float dmn = sqrtf(d0*d0 + d1*d1 + 1e-8f);
    if (dmn > 20.f){ float sc = 20.f/dmn; d0*=sc; d1*=sc; }

    float gt0 = ftanh(g0), gt1 = ftanh(g1);
    float cu0 = ft*cp[0] + it*gt0;
    float cu1 = ft*cp[1] + it*gt1;
    float th = theta[h];
    float sth, cth;
    __sincosf(th, &sth, &cth);
    float c0 = cth*cu0 - sth*cu1;
    float c1 = sth*cu0 + cth*cu1;
    float cs0 = ftanh(c0), cs1 = ftanh(c1);
    float hr0 = ot*cs0, hr1 = ot*cs1;

    float hx = hr0 + 1e-10f, dx = d0 + 1e-10f;
    float hh = sqrtf(hx*hx + hr1*hr1);
    float hd = sqrtf(dx*dx + d1*d1);
    float cosd = (hx*dx + hr1*d1) / fmaxf(hh*hd, 1e-30f);
    float G = 0.5f + 0.5f*cosd;
    float h0 = G*hr0, h1 = G*hr1;
    emer_acc += h0*h0 + h1*h1 + 1e-8f;

    h0 = (h0==h0)?h0:0.f;  h1 = (h1==h1)?h1:0.f;
    c0 = (c0==c0)?c0:0.f;  c1 = (c1==c1)?c1:0.f;
    d0 = (d0==d0)?d0:0.f;  d1 = (d1==d1)?d1:0.f;

    size_t oi = 2*((size_t)b*1024 + h);
    *(f32x2*)(Hout+oi) = f32x2{h0,h1};
    *(f32x2*)(Cout+oi) = f32x2{c0,c1};
    *(f32x2*)(Dout+oi) = f32x2{d0,d1};
  }

  #pragma unroll
  for (int off=32; off; off>>=1){
    conv_acc += __shfl_down(conv_acc, off);
    emer_acc += __shfl_down(emer_acc, off);
  }
  __shared__ float sred[8];
  int wv = tid>>6, ln = tid&63;
  if (ln==0){ sred[wv]=conv_acc; sred[4+wv]=emer_acc; }
  __syncthreads();
  if (tid==0){
    float cv = sred[0]+sred[1]+sred[2]+sred[3];
    float em = sred[4]+sred[5]+sred[6]+sred[7];
    float bm = cv/(cv+em+1e-8f);
    float bt = 0.99f*bp + 0.01f*bm;
    bt = (bt==bt)?bt:0.5f;
    Bout[b] = bt;
  }
}

extern "C" void kernel_launch(void* const* d_in, const int* in_sizes, int n_in,
                              void* d_out, int out_size, void* d_ws, size_t ws_size,
                              hipStream_t stream)
{
  const float* x_t    = (const float*)d_in[0];
  const float* h_prev = (const float*)d_in[1];
  const float* c_prev = (const float*)d_in[2];
  const float* d_prev = (const float*)d_in[3];
  const float* b_prev = (const float*)d_in[4];
  const float* Wf_w   = (const float*)d_in[5];
  const float* Wf_b   = (const float*)d_in[6];
  const float* Wi_w   = (const float*)d_in[7];
  const float* Wi_b   = (const float*)d_in[8];
  const float* Wo_w   = (const float*)d_in[9];
  const float* Wo_b   = (const float*)d_in[10];
  const float* Wc_w   = (const float*)d_in[11];
  const float* Wc_b   = (const float*)d_in[12];
  const float* Wr_w   = (const float*)d_in[13];
  const float* Wr_b   = (const float*)d_in[14];
  const float* theta  = (const float*)d_in[15];

  char* W = (char*)d_ws;
  // OFF0: rawfio f32 [4096][3072]; xc f32 [4096][2048] aliased (dead before fio GEMM)
  float* rawfio = (float*)W;
  float* xc     = (float*)W;
  // OFF1 = 50331648: Wr_hi(4M)|Wr_lo(4M)|x_lo(8M) transient, later raw_g bf16 [4096][2048]
  u16*   Wr_hi  = (u16*)(W + 50331648);
  u16*   Wr_lo  = (u16*)(W + 50331648 + 4194304);
  u16*   x_lo   = (u16*)(W + 50331648 + 8388608);
  u16*   raw_g  = (u16*)(W + 50331648);
  // OFF2 = 67108864: cA bf16 [4096][5120]
  u16*   cA     = (u16*)(W + 67108864);
  // OFF3 = 109051904: WD3 bf16 [3072][5120] (fio), then Wc bf16 [2048][5120] reuse
  u16*   WD     = (u16*)(W + 109051904);
  // OFF4 = 140509184: idx (4097 ints) then smap (4096 ints)
  int*   idx    = (int*)(W + 140509184);
  int*   smap   = (int*)(W + 140509184 + 16388);
  // OFF5 = 140546048: surf_cmp f32 [cap][2048]
  float* Scmp   = (float*)(W + 140546048);
  long long avail = (long long)ws_size - 140546048LL;
  int cap = (int)(avail > 0 ? avail / 8192 : 0);
  if (cap > 1024) cap = 1024;

  dim3 blk(256);

  // 1. x,h -> cA[:,0:3072] + x_lo
  cvt_xh<<<dim3(3,4096), blk, 0, stream>>>(x_t, h_prev, cA, x_lo);
  // 2. Wr -> hi/lo
  cvt_hilo<<<2048, blk, 0, stream>>>(Wr_w, Wr_hi, Wr_lo, 524288);
  // 3. GEMM1 (split 3-pass): xc = x @ Wr^T + b
  gemm_fast<true,false,1><<<dim3(16,32), blk, 0, stream>>>(
      cA, 5120, x_lo, 1024, Wr_hi, 1024, Wr_lo,
      Wr_b, nullptr, nullptr, xc, nullptr, 2048, 1024);
  // 4. flag low-temperature rows
  flag_rows<<<1, blk, 0, stream>>>(b_prev, idx, smap, cap);
  // 5. surfaced -> cA[:,3072:5120] (+ compact f32 for flagged rows)
  prep_surf<<<16384, blk, 0, stream>>>(xc, d_prev, smap, Scmp, cA, cap);
  // 6. Wf,Wi,Wo -> WD3
  cvt_hi<<<5120, blk, 0, stream>>>(Wf_w, WD, 1310720);
  cvt_hi<<<5120, blk, 0, stream>>>(Wi_w, WD + (size_t)1024*5120, 1310720);
  cvt_hi<<<5120, blk, 0, stream>>>(Wo_w, WD + (size_t)2048*5120, 1310720);
  // 7. f/i/o merged (8-phase 256x256), 192 blocks
  gemm8p<4,false,3><<<dim3(12,16), dim3(512), 0, stream>>>(
      cA, 5120, WD, 5120, Wf_b, Wi_b, Wo_b, rawfio, nullptr, 3072, 5120);
  // 8. bias-init flagged rows, then split-K precise fixup
  fix_init<<<4096, blk, 0, stream>>>(smap, idx, Wf_b, Wi_b, Wo_b, rawfio);
  gemm_fix_sk<<<dim3(24,8,FIX_KC), blk, 0, stream>>>(
      x_t, h_prev, Scmp, smap, Wf_w, Wi_w, Wo_w, idx, rawfio);
  // 9. Wc -> WD (reuse), g raw (8-phase 256x128, 256 blocks, bf16 out)
  cvt_hi<<<10240, blk, 0, stream>>>(Wc_w, WD, 2621440);
  gemm8p<2,true,1><<<dim3(16,16), dim3(512), 0, stream>>>(
      cA, 5120, WD, 5120, Wc_b, nullptr, nullptr, nullptr, raw_g, 2048, 5120);
  // 10. epilogue
  epilogue<<<4096, blk, 0, stream>>>(rawfio, raw_g, c_prev, d_prev, b_prev, theta, (float*)d_out);
}